// Round 7
// baseline (187.525 us; speedup 1.0000x reference)
//
#include <hip/hip_runtime.h>
#include <stdint.h>
#include <math.h>

#define NB 16
#define NP 6000
#define NG 128
#define NC 10
#define SELMAX 4     // dyn = int(sum(top5 iou) - 0.5) <= int(4.5) = 4, provable
#define GSTR 24      // padded per-GT stride
#define PCH 1024     // preds per stage1 chunk
#define NCH 6        // chunks (6*1024 >= 6000)
#define CPB 2        // columns per stage1 block

typedef unsigned long long u64;
#define NBPs ((size_t)NB * NP)

__device__ __forceinline__ uint32_t fkey(float f) {
  // monotone float->uint mapping for lexicographic ordering
  uint32_t u = __float_as_uint(f);
  return (u & 0x80000000u) ? ~u : (u | 0x80000000u);
}
__device__ __forceinline__ float fkey_inv(uint32_t k) {
  uint32_t u = (k & 0x80000000u) ? (k & 0x7fffffffu) : ~k;
  return __uint_as_float(u);
}
__device__ __forceinline__ u64 shfl_xor_u64(u64 v, int m) {
  uint32_t lo = (uint32_t)v, hi = (uint32_t)(v >> 32);
  lo = (uint32_t)__shfl_xor((int)lo, m, 64);
  hi = (uint32_t)__shfl_xor((int)hi, m, 64);
  return ((u64)hi << 32) | lo;
}
// 256-thread block min-reduce (used only by rare-path fixup)
__device__ __forceinline__ u64 block_min_u64(u64 v, u64* sred, int lane, int wid) {
  for (int o = 1; o < 64; o <<= 1) {
    u64 t = shfl_xor_u64(v, o);
    if (t < v) v = t;
  }
  __syncthreads();
  if (lane == 0) sred[wid] = v;
  __syncthreads();
  u64 r = sred[0];
  if (sred[1] < r) r = sred[1];
  if (sred[2] < r) r = sred[2];
  if (sred[3] < r) r = sred[3];
  return r;
}

// ---------------------------------------------------------------------------
// Per-GT derived quantities, GSTR floats per (b,g).  Also zeroes colcnt.
__global__ void prep_gt_kernel(const float* __restrict__ gt_boxes,
                               const int* __restrict__ gt_labels,
                               float* __restrict__ gtaux,
                               int* __restrict__ colcnt) {
#pragma clang fp contract(off)
  int b = blockIdx.x, g = threadIdx.x;
  if (g >= NG) return;
  const float* gb = gt_boxes + ((size_t)b * NG + g) * 7;
  float cx = gb[0], cy = gb[1], cz = gb[2];
  float dx = gb[3], dy = gb[4], dz = gb[5];
  float yaw = gb[6];
  float cyw = cosf(yaw), syw = sinf(yaw);
  float ca = fabsf(cyw), sa = fabsf(syw);
  float hx = 0.5f * (dx * ca + dy * sa);
  float hy = 0.5f * (dx * sa + dy * ca);
  float hz = 0.5f * dz;
  float gmin0 = cx - hx, gmin1 = cy - hy, gmin2 = cz - hz;
  float gmax0 = cx + hx, gmax1 = cy + hy, gmax2 = cz + hz;
  float vg = ((gmax0 - gmin0) * (gmax1 - gmin1)) * (gmax2 - gmin2);
  float* o = gtaux + ((size_t)b * NG + g) * GSTR;
  o[0] = gmin0; o[1] = gmin1; o[2] = gmin2;
  o[3] = gmax0; o[4] = gmax1; o[5] = gmax2;
  o[6] = cx - 1.5f * dx; o[7] = cy - 1.5f * dy; o[8] = cz - 1.5f * dz;
  o[9] = cx + 1.5f * dx; o[10] = cy + 1.5f * dy; o[11] = cz + 1.5f * dz;
  o[12] = cx; o[13] = cy; o[14] = cz;
  o[15] = logf(dx); o[16] = logf(dy); o[17] = logf(dz);
  o[18] = syw; o[19] = cyw;
  o[20] = vg;
  o[21] = __int_as_float(gt_labels[(size_t)b * NG + g]);
  o[22] = 0.0f; o[23] = 0.0f;
  colcnt[b * NG + g] = 0;
}

// ---------------------------------------------------------------------------
// Per-pred: focal table -> clst planes, box decode + valid (early-exit over
// LDS-resident GT boxes) -> paux AoS[16] with pen at [15].  Inits row arrays.
__global__ __launch_bounds__(256) void prep_pred_kernel(
    const float* __restrict__ pred_logits,
    const float* __restrict__ pred_boxes,
    const float* __restrict__ gtaux,
    float* __restrict__ paux,
    float* __restrict__ clst,
    int* __restrict__ rowcnt,
    int* __restrict__ rowassign) {
#pragma clang fp contract(off)
  __shared__ float shg[NG * 12];
  const int b = blockIdx.y, tid = threadIdx.x;
  for (int j = tid; j < NG * 12; j += 256) {
    int g = j / 12, k = j % 12;
    shg[j] = gtaux[((size_t)b * NG + g) * GSTR + k];
  }
  __syncthreads();
  const int p = blockIdx.x * 256 + tid;
  if (p >= NP) return;
  const size_t idx = (size_t)b * NP + p;
  const float* lg = pred_logits + idx * NC;
  for (int c = 0; c < NC; ++c) {
    float x = lg[c];
    float pr = 1.0f / (1.0f + expf(-x));
    float neg = (-logf(1.0f - pr + 1e-12f) * 0.75f) * (pr * pr);
    float pos = (-logf(pr + 1e-12f) * 0.25f) * ((1.0f - pr) * (1.0f - pr));
    clst[(size_t)c * NBPs + idx] = (pos - neg) * 2.0f;
  }
  const float* bx = pred_boxes + idx * 10;
  float b0 = bx[0], b1 = bx[1], b2 = bx[2], b3 = bx[3], b4 = bx[4];
  float b5 = bx[5], b6 = bx[6], b7 = bx[7];
  float yaw = atan2f(b6, b7);
  float d0 = expf(b3), d1 = expf(b4), d2 = expf(b5);
  float ca = fabsf(cosf(yaw)), sa = fabsf(sinf(yaw));
  float hx = 0.5f * (d0 * ca + d1 * sa);
  float hy = 0.5f * (d0 * sa + d1 * ca);
  float hz = 0.5f * d2;
  float pmin0 = b0 - hx, pmin1 = b1 - hy, pmin2 = b2 - hz;
  float pmax0 = b0 + hx, pmax1 = b1 + hy, pmax2 = b2 + hz;
  int valid = 0;
  for (int g = 0; g < NG; ++g) {
    const float* s = &shg[g * 12];
    bool inb = (b0 > s[0]) && (b0 < s[3]) && (b1 > s[1]) && (b1 < s[4]) &&
               (b2 > s[2]) && (b2 < s[5]);
    bool inc = (b0 > s[6]) && (b0 < s[9]) && (b1 > s[7]) && (b1 < s[10]) &&
               (b2 > s[8]) && (b2 < s[11]);
    if (inb || inc) { valid = 1; break; }
  }
  float* o = paux + idx * 16;
  o[0] = b0; o[1] = b1; o[2] = b2; o[3] = b3;
  o[4] = b4; o[5] = b5; o[6] = b6; o[7] = b7;
  o[8] = pmin0; o[9] = pmin1; o[10] = pmin2;
  o[11] = pmax0; o[12] = pmax1; o[13] = pmax2;
  o[14] = ((pmax0 - pmin0) * (pmax1 - pmin1)) * (pmax2 - pmin2);
  o[15] = valid ? 0.0f : 10000.0f;        // pen, added after base cost
  rowcnt[idx] = 0;
  rowassign[idx] = 0x7fffffff;
}

// Per-column GT parameters (block-uniform -> SGPR loads).
struct GTp {
  float gmin0, gmin1, gmin2, gmax0, gmax1, gmax2;
  float lo0, lo1, lo2, hi0, hi1, hi2;
  float gtn0, gtn1, gtn2, gtn3, gtn4, gtn5, gtn6, gtn7;
  float vg;
  int label;
};
__device__ __forceinline__ GTp load_gt(const float* __restrict__ gtaux,
                                       int b, int g) {
  const float* ga = gtaux + ((size_t)b * NG + g) * GSTR;
  GTp t;
  t.gmin0 = ga[0]; t.gmin1 = ga[1]; t.gmin2 = ga[2];
  t.gmax0 = ga[3]; t.gmax1 = ga[4]; t.gmax2 = ga[5];
  t.lo0 = ga[6]; t.lo1 = ga[7]; t.lo2 = ga[8];
  t.hi0 = ga[9]; t.hi1 = ga[10]; t.hi2 = ga[11];
  t.gtn0 = ga[12]; t.gtn1 = ga[13]; t.gtn2 = ga[14]; t.gtn3 = ga[15];
  t.gtn4 = ga[16]; t.gtn5 = ga[17]; t.gtn6 = ga[18]; t.gtn7 = ga[19];
  t.vg = ga[20];
  t.label = __float_as_int(ga[21]);
  return t;
}

// Exact reference arithmetic (same op order as all passing rounds); caller
// adds the row-uniform pen last, exactly as the reference does.
__device__ __forceinline__ float cost_base(
    float b0, float b1, float b2, float b3, float b4, float b5, float b6,
    float b7, float pmin0, float pmin1, float pmin2, float pmax0, float pmax1,
    float pmax2, float vp, float cls, const GTp& t, float* iou_out) {
#pragma clang fp contract(off)
  float r = fabsf(b0 - t.gtn0);
  r = r + fabsf(b1 - t.gtn1);
  r = r + fabsf(b2 - t.gtn2);
  r = r + fabsf(b3 - t.gtn3);
  r = r + fabsf(b4 - t.gtn4);
  r = r + fabsf(b5 - t.gtn5);
  r = r + fabsf(b6 - t.gtn6);
  r = r + fabsf(b7 - t.gtn7);
  float reg = r * 0.25f;
  float li0 = fmaxf(pmin0, t.gmin0), li1 = fmaxf(pmin1, t.gmin1),
        li2 = fmaxf(pmin2, t.gmin2);
  float hj0 = fminf(pmax0, t.gmax0), hj1 = fminf(pmax1, t.gmax1),
        hj2 = fminf(pmax2, t.gmax2);
  float e0 = fmaxf(hj0 - li0, 0.0f), e1 = fmaxf(hj1 - li1, 0.0f),
        e2 = fmaxf(hj2 - li2, 0.0f);
  float inter = (e0 * e1) * e2;
  float iou = inter / (((vp + t.vg) - inter) + 1e-7f);
  bool inb = (b0 > t.gmin0) && (b0 < t.gmax0) && (b1 > t.gmin1) &&
             (b1 < t.gmax1) && (b2 > t.gmin2) && (b2 < t.gmax2);
  bool inc = (b0 > t.lo0) && (b0 < t.hi0) && (b1 > t.lo1) && (b1 < t.hi1) &&
             (b2 > t.lo2) && (b2 < t.hi2);
  *iou_out = iou;
  return ((cls + reg) + (-(iou * 0.25f))) + ((inb && inc) ? 0.0f : 100.0f);
}

// ---------------------------------------------------------------------------
// Stage 1: per (chunk, g-pair, b) block.  Costs/ious computed on the fly,
// fkeys staged in LDS (scalar, conflict-free layouts), then each of the 4
// waves extracts independently (no inter-round barriers):
// wave w -> column (w>>1), metric (w&1).  Emits per-chunk top-5 iou values
// and top-4 (cost,p) keys.
__global__ __launch_bounds__(256) void stage1_kernel(
    const float* __restrict__ paux,
    const float* __restrict__ clst,
    const float* __restrict__ gtaux,
    float* __restrict__ iou5,
    u64* __restrict__ ck) {
#pragma clang fp contract(off)
  const int n = blockIdx.x;                   // 6144 = 8 * 768
  const int orig = (n & 7) * 768 + (n >> 3);  // XCD x -> b in {2x, 2x+1}
  const int b = orig / 384;
  const int rem = orig - b * 384;
  const int gq = rem / NCH;
  const int ch = rem - gq * NCH;
  const int g0 = gq * CPB;
  const int tid = threadIdx.x;
  const int lane = tid & 63, wid = tid >> 6;

  __shared__ uint32_t kiouL[CPB][PCH];
  __shared__ uint32_t kcostL[CPB][PCH];

  GTp t0 = load_gt(gtaux, b, g0);
  GTp t1 = load_gt(gtaux, b, g0 + 1);
  const size_t rowbase = (size_t)b * NP;
  const uint32_t PAD_I = fkey(-INFINITY);
  const uint32_t PAD_C = fkey(INFINITY);

  for (int j = 0; j < 4; ++j) {
    const int pl = j * 256 + tid;             // LDS write: stride-1, no conflict
    const int p = ch * PCH + pl;
    uint32_t ki0 = PAD_I, ki1 = PAD_I, kc0 = PAD_C, kc1 = PAD_C;
    if (p < NP) {
      const size_t idx = rowbase + p;
      const float4* pa = (const float4*)(paux + idx * 16);
      float4 A = pa[0], B = pa[1], C = pa[2], D = pa[3];
      float cls0 = clst[(size_t)t0.label * NBPs + idx];
      float cls1 = clst[(size_t)t1.label * NBPs + idx];
      float iou0, iou1;
      float c0 = cost_base(A.x, A.y, A.z, A.w, B.x, B.y, B.z, B.w,
                           C.x, C.y, C.z, C.w, D.x, D.y, D.z,
                           cls0, t0, &iou0);
      float c1 = cost_base(A.x, A.y, A.z, A.w, B.x, B.y, B.z, B.w,
                           C.x, C.y, C.z, C.w, D.x, D.y, D.z,
                           cls1, t1, &iou1);
      ki0 = fkey(iou0); kc0 = fkey(c0 + D.w);
      ki1 = fkey(iou1); kc1 = fkey(c1 + D.w);
    }
    kiouL[0][pl] = ki0;
    kiouL[1][pl] = ki1;
    kcostL[0][pl] = kc0;
    kcostL[1][pl] = kc1;
  }
  __syncthreads();

  const int c = wid >> 1;
  const int col = b * NG + g0 + c;
  const unsigned gbase = (unsigned)(ch * PCH);

  if ((wid & 1) == 0) {
    // top-5 iou, descending extraction with (key < last) filter
    u64 last = ~0ull;
    for (int k = 0; k < 5; ++k) {
      u64 best = 0;
      for (int q = 0; q < 16; ++q) {
        const int pl = q * 64 + lane;         // LDS read: stride-1, no conflict
        u64 key = ((u64)kiouL[c][pl] << 32) | (u64)(gbase + (unsigned)pl);
        if (key < last && key > best) best = key;
      }
      for (int o = 1; o < 64; o <<= 1) {
        u64 t = shfl_xor_u64(best, o);
        if (t > best) best = t;
      }
      if (lane == 0)
        iou5[(size_t)col * 32 + ch * 5 + k] = fkey_inv((uint32_t)(best >> 32));
      last = best;
    }
  } else {
    // top-4 smallest (cost+pen, p), ascending extraction with (key > last)
    u64 last = 0;
    for (int k = 0; k < 4; ++k) {
      u64 best = ~0ull;
      for (int q = 0; q < 16; ++q) {
        const int pl = q * 64 + lane;
        u64 key = ((u64)kcostL[c][pl] << 32) | (u64)(gbase + (unsigned)pl);
        if (key > last && key < best) best = key;
      }
      for (int o = 1; o < 64; o <<= 1) {
        u64 t = shfl_xor_u64(best, o);
        if (t < best) best = t;
      }
      if (lane == 0) ck[(size_t)col * 32 + ch * 4 + k] = best;
      last = best;
    }
  }
}

// ---------------------------------------------------------------------------
// Stage 2: one thread per column.  Merge 6 chunks: global top-5 iou (desc,
// left-assoc sum) -> dyn; global top-dyn (cost,p) keys (stable asc) ->
// colsel + rowcnt/rowassign atomics.
__global__ __launch_bounds__(256) void stage2_kernel(
    const float* __restrict__ iou5,
    const u64* __restrict__ ck,
    const int* __restrict__ head_ptr,
    int* __restrict__ colsel,
    int* __restrict__ rowcnt,
    int* __restrict__ rowassign) {
#pragma clang fp contract(off)
  const int col = blockIdx.x * 256 + threadIdx.x;
  if (col >= NB * NG) return;
  const int b = col / NG, g = col - b * NG;
  const float* ip = iou5 + (size_t)col * 32;
  float m0 = -INFINITY, m1 = -INFINITY, m2 = -INFINITY, m3 = -INFINITY,
        m4 = -INFINITY;
  for (int i = 0; i < 5 * NCH; ++i) {
    float v = ip[i];
    if (v > m4) {
      m4 = v;
      if (m4 > m3) { float t = m4; m4 = m3; m3 = t; }
      if (m3 > m2) { float t = m3; m3 = m2; m2 = t; }
      if (m2 > m1) { float t = m2; m2 = m1; m1 = t; }
      if (m1 > m0) { float t = m1; m1 = m0; m0 = t; }
    }
  }
  float sum5 = ((((m0 + m1) + m2) + m3) + m4);   // desc-order left-assoc
  float adj = sum5 - 0.5f * (float)(6 - head_ptr[0]);
  int dyn = (int)adj;                // trunc toward zero == astype(int32)
  if (dyn < 1) dyn = 1;
  if (dyn > SELMAX) dyn = SELMAX;

  const u64* kp = ck + (size_t)col * 32;
  u64 s0 = ~0ull, s1 = ~0ull, s2 = ~0ull, s3 = ~0ull;
  for (int i = 0; i < SELMAX * NCH; ++i) {
    u64 k = kp[i];
    if (k < s3) {
      s3 = k;
      if (s3 < s2) { u64 t = s3; s3 = s2; s2 = t; }
      if (s2 < s1) { u64 t = s2; s2 = s1; s1 = t; }
      if (s1 < s0) { u64 t = s1; s1 = s0; s0 = t; }
    }
  }
  const size_t rowbase = (size_t)b * NP;
  int p0 = (int)(s0 & 0xffffffffu);
  int p1 = (int)(s1 & 0xffffffffu);
  int p2 = (int)(s2 & 0xffffffffu);
  int p3 = (int)(s3 & 0xffffffffu);
  int sel0 = (dyn > 0) ? p0 : -1;
  int sel1 = (dyn > 1) ? p1 : -1;
  int sel2 = (dyn > 2) ? p2 : -1;
  int sel3 = (dyn > 3) ? p3 : -1;
  colsel[(size_t)col * SELMAX + 0] = sel0;
  colsel[(size_t)col * SELMAX + 1] = sel1;
  colsel[(size_t)col * SELMAX + 2] = sel2;
  colsel[(size_t)col * SELMAX + 3] = sel3;
  if (sel0 >= 0) { atomicAdd(&rowcnt[rowbase + sel0], 1); atomicMin(&rowassign[rowbase + sel0], g); }
  if (sel1 >= 0) { atomicAdd(&rowcnt[rowbase + sel1], 1); atomicMin(&rowassign[rowbase + sel1], g); }
  if (sel2 >= 0) { atomicAdd(&rowcnt[rowbase + sel2], 1); atomicMin(&rowassign[rowbase + sel2], g); }
  if (sel3 >= 0) { atomicAdd(&rowcnt[rowbase + sel3], 1); atomicMin(&rowassign[rowbase + sel3], g); }
}

// ---------------------------------------------------------------------------
// Epilogue part 1 (fused): blockIdx.x<24 -> prior rows (rowcnt>1) recompute
// their 128 costs, argmin -> rowmin, scatter into colcnt.  blockIdx.x==24 ->
// colcnt part (a): selections whose row stayed single.  Both atomicAdd.
__global__ __launch_bounds__(256) void epi1_kernel(
    const float* __restrict__ paux,
    const float* __restrict__ clst,
    const float* __restrict__ gtaux,
    const int* __restrict__ colsel,
    const int* __restrict__ rowcnt,
    int* __restrict__ rowminArr,
    int* __restrict__ colcnt) {
#pragma clang fp contract(off)
  const int b = blockIdx.y, tid = threadIdx.x;
  if (blockIdx.x == 24) {
    const int g = tid;
    if (g < NG) {
      int cnt = 0;
      const size_t cb = (size_t)(b * NG + g) * SELMAX;
      for (int k = 0; k < SELMAX; ++k) {
        int s = colsel[cb + k];
        if (s >= 0 && rowcnt[(size_t)b * NP + s] == 1) cnt++;
      }
      if (cnt) atomicAdd(&colcnt[b * NG + g], cnt);
    }
    return;
  }
  const int p = blockIdx.x * 256 + tid;
  if (p >= NP) return;
  const size_t idx = (size_t)b * NP + p;
  if (rowcnt[idx] <= 1) return;
  const float4* pa = (const float4*)(paux + idx * 16);
  float4 A = pa[0], Bq = pa[1], Cq = pa[2], Dq = pa[3];
  const float pen = Dq.w;
  float best = INFINITY;
  int bg = 0;
  for (int g = 0; g < NG; ++g) {
    GTp t = load_gt(gtaux, b, g);
    float cls = clst[(size_t)t.label * NBPs + idx];
    float iou;
    float cc = cost_base(A.x, A.y, A.z, A.w, Bq.x, Bq.y, Bq.z, Bq.w,
                         Cq.x, Cq.y, Cq.z, Cq.w, Dq.x, Dq.y, Dq.z,
                         cls, t, &iou);
    float cv = cc + pen;
    if (cv < best) { best = cv; bg = g; }   // strict <: first-g tiebreak
  }
  rowminArr[idx] = bg;
  atomicAdd(&colcnt[b * NG + bg], 1);
}

// Empty columns: recompute costs over never-matched rows, argmin (cost+pen,p).
__global__ __launch_bounds__(256) void fixup_kernel(
    const float* __restrict__ paux,
    const float* __restrict__ clst,
    const float* __restrict__ gtaux,
    const int* __restrict__ colcnt,
    const int* __restrict__ rowcnt,
    int* __restrict__ rowassign) {
#pragma clang fp contract(off)
  const int g = blockIdx.x, b = blockIdx.y, tid = threadIdx.x;
  if (colcnt[b * NG + g] != 0) return;  // uniform across block
  const int lane = tid & 63, wid = tid >> 6;
  const size_t rowbase = (size_t)b * NP;
  GTp t = load_gt(gtaux, b, g);
  u64 best = ~0ull;
  for (int p = tid; p < NP; p += 256) {
    const size_t idx = rowbase + p;
    if (rowcnt[idx] == 0) {
      const float4* pa = (const float4*)(paux + idx * 16);
      float4 A = pa[0], Bq = pa[1], Cq = pa[2], Dq = pa[3];
      float cls = clst[(size_t)t.label * NBPs + idx];
      float iou;
      float cc = cost_base(A.x, A.y, A.z, A.w, Bq.x, Bq.y, Bq.z, Bq.w,
                           Cq.x, Cq.y, Cq.z, Cq.w, Dq.x, Dq.y, Dq.z,
                           cls, t, &iou);
      u64 key = ((u64)fkey(cc + Dq.w) << 32) | (unsigned)p;
      if (key < best) best = key;
    }
  }
  __shared__ u64 sred[4];
  u64 rr = block_min_u64(best, sred, lane, wid);
  if (tid == 0) {
    int pos = (int)(rr & 0xffffffffu);
    atomicMin(&rowassign[rowbase + pos], g);  // min g == argmax first-1
  }
}

__global__ void output_kernel(const int* __restrict__ rowcnt,
                              const int* __restrict__ rowassign,
                              const int* __restrict__ rowminArr,
                              int* __restrict__ out) {
  const int i = blockIdx.x * 256 + threadIdx.x;
  if (i >= (int)NBPs) return;
  int rc = rowcnt[i];
  int fg, m;
  if (rc == 0) {
    int ra = rowassign[i];
    if (ra == 0x7fffffff) { fg = 0; m = -1; }
    else { fg = 1; m = ra; }          // fixup-assigned (min g)
  } else if (rc == 1) {
    fg = 1; m = rowassign[i];         // single selecting column
  } else {
    fg = 1; m = rowminArr[i];         // prior row -> one-hot at row argmin
  }
  out[i] = fg;
  out[NBPs + i] = m;
}

// ---------------------------------------------------------------------------
extern "C" void kernel_launch(void* const* d_in, const int* in_sizes, int n_in,
                              void* d_out, int out_size, void* d_ws, size_t ws_size,
                              hipStream_t stream) {
  const float* pred_logits = (const float*)d_in[0];
  const float* pred_boxes = (const float*)d_in[1];
  const float* gt_boxes = (const float*)d_in[2];
  const int* gt_labels = (const int*)d_in[3];
  const int* head = (const int*)d_in[4];
  (void)in_sizes; (void)n_in; (void)out_size; (void)ws_size;

  char* w = (char*)d_ws;
  size_t off = 0;
  auto alloc = [&](size_t bytes) -> void* {
    void* p = w + off;
    off += (bytes + 255) & ~(size_t)255;
    return p;
  };
  float* paux = (float*)alloc((size_t)NB * NP * 16 * 4);       // 6.1 MB
  float* clst = (float*)alloc((size_t)NC * NB * NP * 4);       // 3.8 MB
  float* gtaux = (float*)alloc((size_t)NB * NG * GSTR * 4);
  float* iou5 = (float*)alloc((size_t)NB * NG * 32 * 4);       // 256 KB
  u64* ck = (u64*)alloc((size_t)NB * NG * 32 * 8);             // 512 KB
  int* colsel = (int*)alloc((size_t)NB * NG * SELMAX * 4);
  int* rowcnt = (int*)alloc((size_t)NB * NP * 4);
  int* rowassign = (int*)alloc((size_t)NB * NP * 4);
  int* rowminArr = (int*)alloc((size_t)NB * NP * 4);
  int* colcnt = (int*)alloc((size_t)NB * NG * 4);

  int* out = (int*)d_out;
  dim3 blk(256);
  prep_gt_kernel<<<dim3(NB), dim3(128), 0, stream>>>(gt_boxes, gt_labels, gtaux, colcnt);
  prep_pred_kernel<<<dim3((NP + 255) / 256, NB), blk, 0, stream>>>(
      pred_logits, pred_boxes, gtaux, paux, clst, rowcnt, rowassign);
  stage1_kernel<<<dim3(NB * (NG / CPB) * NCH), blk, 0, stream>>>(
      paux, clst, gtaux, iou5, ck);
  stage2_kernel<<<dim3((NB * NG + 255) / 256), blk, 0, stream>>>(
      iou5, ck, head, colsel, rowcnt, rowassign);
  epi1_kernel<<<dim3(25, NB), blk, 0, stream>>>(
      paux, clst, gtaux, colsel, rowcnt, rowminArr, colcnt);
  fixup_kernel<<<dim3(NG, NB), blk, 0, stream>>>(
      paux, clst, gtaux, colcnt, rowcnt, rowassign);
  output_kernel<<<dim3(((int)NBPs + 255) / 256), blk, 0, stream>>>(
      rowcnt, rowassign, rowminArr, out);
}

// Round 8
// 135.837 us; speedup vs baseline: 1.3805x; 1.3805x over previous
//
#include <hip/hip_runtime.h>
#include <stdint.h>
#include <math.h>

#define NB 16
#define NP 6000
#define NG 128
#define NC 10
#define SELMAX 4     // dyn = int(sum(top5 iou) - 0.5) <= int(4.5) = 4, provable
#define GSTR 24      // padded per-GT stride
#define PCH 1024     // preds per stage1 chunk
#define NCH 6        // chunks (6*1024 >= 6000)
#define CPB 2        // columns per stage1 block
#define EPIW 128     // worklist blocks in epi_kernel (512 waves)

typedef unsigned long long u64;
#define NBPs ((size_t)NB * NP)

__device__ __forceinline__ uint32_t fkey(float f) {
  // monotone float->uint mapping for lexicographic ordering
  uint32_t u = __float_as_uint(f);
  return (u & 0x80000000u) ? ~u : (u | 0x80000000u);
}
__device__ __forceinline__ float fkey_inv(uint32_t k) {
  uint32_t u = (k & 0x80000000u) ? (k & 0x7fffffffu) : ~k;
  return __uint_as_float(u);
}
__device__ __forceinline__ u64 shfl_xor_u64(u64 v, int m) {
  uint32_t lo = (uint32_t)v, hi = (uint32_t)(v >> 32);
  lo = (uint32_t)__shfl_xor((int)lo, m, 64);
  hi = (uint32_t)__shfl_xor((int)hi, m, 64);
  return ((u64)hi << 32) | lo;
}
// 256-thread block min-reduce (used only by rare-path fixup)
__device__ __forceinline__ u64 block_min_u64(u64 v, u64* sred, int lane, int wid) {
  for (int o = 1; o < 64; o <<= 1) {
    u64 t = shfl_xor_u64(v, o);
    if (t < v) v = t;
  }
  __syncthreads();
  if (lane == 0) sred[wid] = v;
  __syncthreads();
  u64 r = sred[0];
  if (sred[1] < r) r = sred[1];
  if (sred[2] < r) r = sred[2];
  if (sred[3] < r) r = sred[3];
  return r;
}

// ---------------------------------------------------------------------------
// Per-GT derived quantities, GSTR floats per (b,g).  Also zeroes colcnt/wcount.
__global__ void prep_gt_kernel(const float* __restrict__ gt_boxes,
                               const int* __restrict__ gt_labels,
                               float* __restrict__ gtaux,
                               int* __restrict__ colcnt,
                               int* __restrict__ wcount) {
#pragma clang fp contract(off)
  int b = blockIdx.x, g = threadIdx.x;
  if (b == 0 && g == 0) wcount[0] = 0;
  if (g >= NG) return;
  const float* gb = gt_boxes + ((size_t)b * NG + g) * 7;
  float cx = gb[0], cy = gb[1], cz = gb[2];
  float dx = gb[3], dy = gb[4], dz = gb[5];
  float yaw = gb[6];
  float cyw = cosf(yaw), syw = sinf(yaw);
  float ca = fabsf(cyw), sa = fabsf(syw);
  float hx = 0.5f * (dx * ca + dy * sa);
  float hy = 0.5f * (dx * sa + dy * ca);
  float hz = 0.5f * dz;
  float gmin0 = cx - hx, gmin1 = cy - hy, gmin2 = cz - hz;
  float gmax0 = cx + hx, gmax1 = cy + hy, gmax2 = cz + hz;
  float vg = ((gmax0 - gmin0) * (gmax1 - gmin1)) * (gmax2 - gmin2);
  float* o = gtaux + ((size_t)b * NG + g) * GSTR;
  o[0] = gmin0; o[1] = gmin1; o[2] = gmin2;
  o[3] = gmax0; o[4] = gmax1; o[5] = gmax2;
  o[6] = cx - 1.5f * dx; o[7] = cy - 1.5f * dy; o[8] = cz - 1.5f * dz;
  o[9] = cx + 1.5f * dx; o[10] = cy + 1.5f * dy; o[11] = cz + 1.5f * dz;
  o[12] = cx; o[13] = cy; o[14] = cz;
  o[15] = logf(dx); o[16] = logf(dy); o[17] = logf(dz);
  o[18] = syw; o[19] = cyw;
  o[20] = vg;
  o[21] = __int_as_float(gt_labels[(size_t)b * NG + g]);
  o[22] = 0.0f; o[23] = 0.0f;
  colcnt[b * NG + g] = 0;
}

// ---------------------------------------------------------------------------
// Per-pred: focal table -> clst planes, box decode + valid (early-exit over
// LDS-resident GT boxes) -> paux AoS[16] with pen at [15].  Inits row arrays.
__global__ __launch_bounds__(256) void prep_pred_kernel(
    const float* __restrict__ pred_logits,
    const float* __restrict__ pred_boxes,
    const float* __restrict__ gtaux,
    float* __restrict__ paux,
    float* __restrict__ clst,
    int* __restrict__ rowcnt,
    int* __restrict__ rowassign) {
#pragma clang fp contract(off)
  __shared__ float shg[NG * 12];
  const int b = blockIdx.y, tid = threadIdx.x;
  for (int j = tid; j < NG * 12; j += 256) {
    int g = j / 12, k = j % 12;
    shg[j] = gtaux[((size_t)b * NG + g) * GSTR + k];
  }
  __syncthreads();
  const int p = blockIdx.x * 256 + tid;
  if (p >= NP) return;
  const size_t idx = (size_t)b * NP + p;
  const float* lg = pred_logits + idx * NC;
  for (int c = 0; c < NC; ++c) {
    float x = lg[c];
    float pr = 1.0f / (1.0f + expf(-x));
    float neg = (-logf(1.0f - pr + 1e-12f) * 0.75f) * (pr * pr);
    float pos = (-logf(pr + 1e-12f) * 0.25f) * ((1.0f - pr) * (1.0f - pr));
    clst[(size_t)c * NBPs + idx] = (pos - neg) * 2.0f;
  }
  const float* bx = pred_boxes + idx * 10;
  float b0 = bx[0], b1 = bx[1], b2 = bx[2], b3 = bx[3], b4 = bx[4];
  float b5 = bx[5], b6 = bx[6], b7 = bx[7];
  float yaw = atan2f(b6, b7);
  float d0 = expf(b3), d1 = expf(b4), d2 = expf(b5);
  float ca = fabsf(cosf(yaw)), sa = fabsf(sinf(yaw));
  float hx = 0.5f * (d0 * ca + d1 * sa);
  float hy = 0.5f * (d0 * sa + d1 * ca);
  float hz = 0.5f * d2;
  float pmin0 = b0 - hx, pmin1 = b1 - hy, pmin2 = b2 - hz;
  float pmax0 = b0 + hx, pmax1 = b1 + hy, pmax2 = b2 + hz;
  int valid = 0;
  for (int g = 0; g < NG; ++g) {
    const float* s = &shg[g * 12];
    bool inb = (b0 > s[0]) && (b0 < s[3]) && (b1 > s[1]) && (b1 < s[4]) &&
               (b2 > s[2]) && (b2 < s[5]);
    bool inc = (b0 > s[6]) && (b0 < s[9]) && (b1 > s[7]) && (b1 < s[10]) &&
               (b2 > s[8]) && (b2 < s[11]);
    if (inb || inc) { valid = 1; break; }
  }
  float* o = paux + idx * 16;
  o[0] = b0; o[1] = b1; o[2] = b2; o[3] = b3;
  o[4] = b4; o[5] = b5; o[6] = b6; o[7] = b7;
  o[8] = pmin0; o[9] = pmin1; o[10] = pmin2;
  o[11] = pmax0; o[12] = pmax1; o[13] = pmax2;
  o[14] = ((pmax0 - pmin0) * (pmax1 - pmin1)) * (pmax2 - pmin2);
  o[15] = valid ? 0.0f : 10000.0f;        // pen, added after base cost
  rowcnt[idx] = 0;
  rowassign[idx] = 0x7fffffff;
}

// Per-column GT parameters.
struct GTp {
  float gmin0, gmin1, gmin2, gmax0, gmax1, gmax2;
  float lo0, lo1, lo2, hi0, hi1, hi2;
  float gtn0, gtn1, gtn2, gtn3, gtn4, gtn5, gtn6, gtn7;
  float vg;
  int label;
};
__device__ __forceinline__ GTp load_gt(const float* __restrict__ gtaux,
                                       int b, int g) {
  const float* ga = gtaux + ((size_t)b * NG + g) * GSTR;
  GTp t;
  t.gmin0 = ga[0]; t.gmin1 = ga[1]; t.gmin2 = ga[2];
  t.gmax0 = ga[3]; t.gmax1 = ga[4]; t.gmax2 = ga[5];
  t.lo0 = ga[6]; t.lo1 = ga[7]; t.lo2 = ga[8];
  t.hi0 = ga[9]; t.hi1 = ga[10]; t.hi2 = ga[11];
  t.gtn0 = ga[12]; t.gtn1 = ga[13]; t.gtn2 = ga[14]; t.gtn3 = ga[15];
  t.gtn4 = ga[16]; t.gtn5 = ga[17]; t.gtn6 = ga[18]; t.gtn7 = ga[19];
  t.vg = ga[20];
  t.label = __float_as_int(ga[21]);
  return t;
}

// Exact reference arithmetic (same op order as all passing rounds); caller
// adds the row-uniform pen last, exactly as the reference does.
__device__ __forceinline__ float cost_base(
    float b0, float b1, float b2, float b3, float b4, float b5, float b6,
    float b7, float pmin0, float pmin1, float pmin2, float pmax0, float pmax1,
    float pmax2, float vp, float cls, const GTp& t, float* iou_out) {
#pragma clang fp contract(off)
  float r = fabsf(b0 - t.gtn0);
  r = r + fabsf(b1 - t.gtn1);
  r = r + fabsf(b2 - t.gtn2);
  r = r + fabsf(b3 - t.gtn3);
  r = r + fabsf(b4 - t.gtn4);
  r = r + fabsf(b5 - t.gtn5);
  r = r + fabsf(b6 - t.gtn6);
  r = r + fabsf(b7 - t.gtn7);
  float reg = r * 0.25f;
  float li0 = fmaxf(pmin0, t.gmin0), li1 = fmaxf(pmin1, t.gmin1),
        li2 = fmaxf(pmin2, t.gmin2);
  float hj0 = fminf(pmax0, t.gmax0), hj1 = fminf(pmax1, t.gmax1),
        hj2 = fminf(pmax2, t.gmax2);
  float e0 = fmaxf(hj0 - li0, 0.0f), e1 = fmaxf(hj1 - li1, 0.0f),
        e2 = fmaxf(hj2 - li2, 0.0f);
  float inter = (e0 * e1) * e2;
  float iou = inter / (((vp + t.vg) - inter) + 1e-7f);
  bool inb = (b0 > t.gmin0) && (b0 < t.gmax0) && (b1 > t.gmin1) &&
             (b1 < t.gmax1) && (b2 > t.gmin2) && (b2 < t.gmax2);
  bool inc = (b0 > t.lo0) && (b0 < t.hi0) && (b1 > t.lo1) && (b1 < t.hi1) &&
             (b2 > t.lo2) && (b2 < t.hi2);
  *iou_out = iou;
  return ((cls + reg) + (-(iou * 0.25f))) + ((inb && inc) ? 0.0f : 100.0f);
}

// ---------------------------------------------------------------------------
// Stage 1: per (chunk, g-pair, b) block.  Costs/ious computed on the fly,
// fkeys staged in LDS (scalar, conflict-free layouts), then each of the 4
// waves extracts independently (no inter-round barriers):
// wave w -> column (w>>1), metric (w&1).  Emits per-chunk top-5 iou values
// and top-4 (cost,p) keys.
__global__ __launch_bounds__(256) void stage1_kernel(
    const float* __restrict__ paux,
    const float* __restrict__ clst,
    const float* __restrict__ gtaux,
    float* __restrict__ iou5,
    u64* __restrict__ ck) {
#pragma clang fp contract(off)
  const int n = blockIdx.x;                   // 6144 = 8 * 768
  const int orig = (n & 7) * 768 + (n >> 3);  // XCD x -> b in {2x, 2x+1}
  const int b = orig / 384;
  const int rem = orig - b * 384;
  const int gq = rem / NCH;
  const int ch = rem - gq * NCH;
  const int g0 = gq * CPB;
  const int tid = threadIdx.x;
  const int lane = tid & 63, wid = tid >> 6;

  __shared__ uint32_t kiouL[CPB][PCH];
  __shared__ uint32_t kcostL[CPB][PCH];

  GTp t0 = load_gt(gtaux, b, g0);
  GTp t1 = load_gt(gtaux, b, g0 + 1);
  const size_t rowbase = (size_t)b * NP;
  const uint32_t PAD_I = fkey(-INFINITY);
  const uint32_t PAD_C = fkey(INFINITY);

  for (int j = 0; j < 4; ++j) {
    const int pl = j * 256 + tid;             // LDS write: stride-1, no conflict
    const int p = ch * PCH + pl;
    uint32_t ki0 = PAD_I, ki1 = PAD_I, kc0 = PAD_C, kc1 = PAD_C;
    if (p < NP) {
      const size_t idx = rowbase + p;
      const float4* pa = (const float4*)(paux + idx * 16);
      float4 A = pa[0], B = pa[1], C = pa[2], D = pa[3];
      float cls0 = clst[(size_t)t0.label * NBPs + idx];
      float cls1 = clst[(size_t)t1.label * NBPs + idx];
      float iou0, iou1;
      float c0 = cost_base(A.x, A.y, A.z, A.w, B.x, B.y, B.z, B.w,
                           C.x, C.y, C.z, C.w, D.x, D.y, D.z,
                           cls0, t0, &iou0);
      float c1 = cost_base(A.x, A.y, A.z, A.w, B.x, B.y, B.z, B.w,
                           C.x, C.y, C.z, C.w, D.x, D.y, D.z,
                           cls1, t1, &iou1);
      ki0 = fkey(iou0); kc0 = fkey(c0 + D.w);
      ki1 = fkey(iou1); kc1 = fkey(c1 + D.w);
    }
    kiouL[0][pl] = ki0;
    kiouL[1][pl] = ki1;
    kcostL[0][pl] = kc0;
    kcostL[1][pl] = kc1;
  }
  __syncthreads();

  const int c = wid >> 1;
  const int col = b * NG + g0 + c;
  const unsigned gbase = (unsigned)(ch * PCH);

  if ((wid & 1) == 0) {
    // top-5 iou, descending extraction with (key < last) filter
    u64 last = ~0ull;
    for (int k = 0; k < 5; ++k) {
      u64 best = 0;
      for (int q = 0; q < 16; ++q) {
        const int pl = q * 64 + lane;         // LDS read: stride-1, no conflict
        u64 key = ((u64)kiouL[c][pl] << 32) | (u64)(gbase + (unsigned)pl);
        if (key < last && key > best) best = key;
      }
      for (int o = 1; o < 64; o <<= 1) {
        u64 t = shfl_xor_u64(best, o);
        if (t > best) best = t;
      }
      if (lane == 0)
        iou5[(size_t)col * 32 + ch * 5 + k] = fkey_inv((uint32_t)(best >> 32));
      last = best;
    }
  } else {
    // top-4 smallest (cost+pen, p), ascending extraction with (key > last)
    u64 last = 0;
    for (int k = 0; k < 4; ++k) {
      u64 best = ~0ull;
      for (int q = 0; q < 16; ++q) {
        const int pl = q * 64 + lane;
        u64 key = ((u64)kcostL[c][pl] << 32) | (u64)(gbase + (unsigned)pl);
        if (key > last && key < best) best = key;
      }
      for (int o = 1; o < 64; o <<= 1) {
        u64 t = shfl_xor_u64(best, o);
        if (t < best) best = t;
      }
      if (lane == 0) ck[(size_t)col * 32 + ch * 4 + k] = best;
      last = best;
    }
  }
}

// ---------------------------------------------------------------------------
// Stage 2: one thread per column.  Merge 6 chunks: global top-5 iou (desc,
// left-assoc sum) -> dyn; global top-dyn (cost,p) keys (stable asc) ->
// colsel + rowcnt/rowassign atomics.  Rows crossing rowcnt 1->2 are enqueued
// exactly once into the prior-row worklist.
__global__ __launch_bounds__(256) void stage2_kernel(
    const float* __restrict__ iou5,
    const u64* __restrict__ ck,
    const int* __restrict__ head_ptr,
    int* __restrict__ colsel,
    int* __restrict__ rowcnt,
    int* __restrict__ rowassign,
    int* __restrict__ wlist,
    int* __restrict__ wcount) {
#pragma clang fp contract(off)
  const int col = blockIdx.x * 256 + threadIdx.x;
  if (col >= NB * NG) return;
  const int b = col / NG, g = col - b * NG;
  const float* ip = iou5 + (size_t)col * 32;
  float m0 = -INFINITY, m1 = -INFINITY, m2 = -INFINITY, m3 = -INFINITY,
        m4 = -INFINITY;
  for (int i = 0; i < 5 * NCH; ++i) {
    float v = ip[i];
    if (v > m4) {
      m4 = v;
      if (m4 > m3) { float t = m4; m4 = m3; m3 = t; }
      if (m3 > m2) { float t = m3; m3 = m2; m2 = t; }
      if (m2 > m1) { float t = m2; m2 = m1; m1 = t; }
      if (m1 > m0) { float t = m1; m1 = m0; m0 = t; }
    }
  }
  float sum5 = ((((m0 + m1) + m2) + m3) + m4);   // desc-order left-assoc
  float adj = sum5 - 0.5f * (float)(6 - head_ptr[0]);
  int dyn = (int)adj;                // trunc toward zero == astype(int32)
  if (dyn < 1) dyn = 1;
  if (dyn > SELMAX) dyn = SELMAX;

  const u64* kp = ck + (size_t)col * 32;
  u64 s0 = ~0ull, s1 = ~0ull, s2 = ~0ull, s3 = ~0ull;
  for (int i = 0; i < SELMAX * NCH; ++i) {
    u64 k = kp[i];
    if (k < s3) {
      s3 = k;
      if (s3 < s2) { u64 t = s3; s3 = s2; s2 = t; }
      if (s2 < s1) { u64 t = s2; s2 = s1; s1 = t; }
      if (s1 < s0) { u64 t = s1; s1 = s0; s0 = t; }
    }
  }
  const size_t rowbase = (size_t)b * NP;
  int pk[4];
  pk[0] = (int)(s0 & 0xffffffffu);
  pk[1] = (int)(s1 & 0xffffffffu);
  pk[2] = (int)(s2 & 0xffffffffu);
  pk[3] = (int)(s3 & 0xffffffffu);
  for (int k = 0; k < SELMAX; ++k) {
    int sel = (k < dyn) ? pk[k] : -1;
    colsel[(size_t)col * SELMAX + k] = sel;
    if (sel >= 0) {
      int old = atomicAdd(&rowcnt[rowbase + sel], 1);
      if (old == 1) {
        int slot = atomicAdd(wcount, 1);
        wlist[slot] = (int)(rowbase + sel);
      }
      atomicMin(&rowassign[rowbase + sel], g);
    }
  }
}

// ---------------------------------------------------------------------------
// Epilogue: blocks [0,EPIW): one WAVE per prior row from the worklist —
// 128 g's spread 2-per-lane, parallel gathers, u64-key min reduce (key
// includes g -> first-g tiebreak).  Blocks [EPIW, EPIW+8): colcnt part (a).
__global__ __launch_bounds__(256) void epi_kernel(
    const float* __restrict__ paux,
    const float* __restrict__ clst,
    const float* __restrict__ gtaux,
    const int* __restrict__ colsel,
    const int* __restrict__ rowcnt,
    const int* __restrict__ wlist,
    const int* __restrict__ wcount,
    int* __restrict__ rowminArr,
    int* __restrict__ colcnt) {
#pragma clang fp contract(off)
  const int tid = threadIdx.x;
  if (blockIdx.x >= EPIW) {
    // colcnt part (a): selections whose row stayed single (rowcnt==1)
    const int col = (blockIdx.x - EPIW) * 256 + tid;
    if (col < NB * NG) {
      const int b = col / NG;
      int cnt = 0;
      const size_t cb = (size_t)col * SELMAX;
      for (int k = 0; k < SELMAX; ++k) {
        int s = colsel[cb + k];
        if (s >= 0 && rowcnt[(size_t)b * NP + s] == 1) cnt++;
      }
      if (cnt) atomicAdd(&colcnt[col], cnt);
    }
    return;
  }
  const int lane = tid & 63, wid = tid >> 6;
  const int wavesTotal = EPIW * 4;
  const int wave = blockIdx.x * 4 + wid;
  const int n = wcount[0];
  for (int e = wave; e < n; e += wavesTotal) {
    const int idx = wlist[e];
    const int b = idx / NP;
    const float4* pa = (const float4*)(paux + (size_t)idx * 16);
    float4 A = pa[0], Bq = pa[1], Cq = pa[2], Dq = pa[3];
    const float pen = Dq.w;
    u64 best = ~0ull;
    for (int h = 0; h < 2; ++h) {
      const int g = h * 64 + lane;
      GTp t = load_gt(gtaux, b, g);
      float cls = clst[(size_t)t.label * NBPs + idx];
      float iou;
      float cc = cost_base(A.x, A.y, A.z, A.w, Bq.x, Bq.y, Bq.z, Bq.w,
                           Cq.x, Cq.y, Cq.z, Cq.w, Dq.x, Dq.y, Dq.z,
                           cls, t, &iou);
      u64 key = ((u64)fkey(cc + pen) << 32) | (unsigned)g;
      if (key < best) best = key;
    }
    for (int o = 1; o < 64; o <<= 1) {
      u64 t = shfl_xor_u64(best, o);
      if (t < best) best = t;
    }
    if (lane == 0) {
      const int bg = (int)(best & 0xffffffffu);
      rowminArr[idx] = bg;
      atomicAdd(&colcnt[b * NG + bg], 1);
    }
  }
}

// Empty columns: recompute costs over never-matched rows, argmin (cost+pen,p).
__global__ __launch_bounds__(256) void fixup_kernel(
    const float* __restrict__ paux,
    const float* __restrict__ clst,
    const float* __restrict__ gtaux,
    const int* __restrict__ colcnt,
    const int* __restrict__ rowcnt,
    int* __restrict__ rowassign) {
#pragma clang fp contract(off)
  const int g = blockIdx.x, b = blockIdx.y, tid = threadIdx.x;
  if (colcnt[b * NG + g] != 0) return;  // uniform across block
  const int lane = tid & 63, wid = tid >> 6;
  const size_t rowbase = (size_t)b * NP;
  GTp t = load_gt(gtaux, b, g);
  u64 best = ~0ull;
  for (int p = tid; p < NP; p += 256) {
    const size_t idx = rowbase + p;
    if (rowcnt[idx] == 0) {
      const float4* pa = (const float4*)(paux + idx * 16);
      float4 A = pa[0], Bq = pa[1], Cq = pa[2], Dq = pa[3];
      float cls = clst[(size_t)t.label * NBPs + idx];
      float iou;
      float cc = cost_base(A.x, A.y, A.z, A.w, Bq.x, Bq.y, Bq.z, Bq.w,
                           Cq.x, Cq.y, Cq.z, Cq.w, Dq.x, Dq.y, Dq.z,
                           cls, t, &iou);
      u64 key = ((u64)fkey(cc + Dq.w) << 32) | (unsigned)p;
      if (key < best) best = key;
    }
  }
  __shared__ u64 sred[4];
  u64 rr = block_min_u64(best, sred, lane, wid);
  if (tid == 0) {
    int pos = (int)(rr & 0xffffffffu);
    atomicMin(&rowassign[rowbase + pos], g);  // min g == argmax first-1
  }
}

__global__ void output_kernel(const int* __restrict__ rowcnt,
                              const int* __restrict__ rowassign,
                              const int* __restrict__ rowminArr,
                              int* __restrict__ out) {
  const int i = blockIdx.x * 256 + threadIdx.x;
  if (i >= (int)NBPs) return;
  int rc = rowcnt[i];
  int fg, m;
  if (rc == 0) {
    int ra = rowassign[i];
    if (ra == 0x7fffffff) { fg = 0; m = -1; }
    else { fg = 1; m = ra; }          // fixup-assigned (min g)
  } else if (rc == 1) {
    fg = 1; m = rowassign[i];         // single selecting column
  } else {
    fg = 1; m = rowminArr[i];         // prior row -> one-hot at row argmin
  }
  out[i] = fg;
  out[NBPs + i] = m;
}

// ---------------------------------------------------------------------------
extern "C" void kernel_launch(void* const* d_in, const int* in_sizes, int n_in,
                              void* d_out, int out_size, void* d_ws, size_t ws_size,
                              hipStream_t stream) {
  const float* pred_logits = (const float*)d_in[0];
  const float* pred_boxes = (const float*)d_in[1];
  const float* gt_boxes = (const float*)d_in[2];
  const int* gt_labels = (const int*)d_in[3];
  const int* head = (const int*)d_in[4];
  (void)in_sizes; (void)n_in; (void)out_size; (void)ws_size;

  char* w = (char*)d_ws;
  size_t off = 0;
  auto alloc = [&](size_t bytes) -> void* {
    void* p = w + off;
    off += (bytes + 255) & ~(size_t)255;
    return p;
  };
  float* paux = (float*)alloc((size_t)NB * NP * 16 * 4);       // 6.1 MB
  float* clst = (float*)alloc((size_t)NC * NB * NP * 4);       // 3.8 MB
  float* gtaux = (float*)alloc((size_t)NB * NG * GSTR * 4);
  float* iou5 = (float*)alloc((size_t)NB * NG * 32 * 4);       // 256 KB
  u64* ck = (u64*)alloc((size_t)NB * NG * 32 * 8);             // 512 KB
  int* colsel = (int*)alloc((size_t)NB * NG * SELMAX * 4);
  int* rowcnt = (int*)alloc((size_t)NB * NP * 4);
  int* rowassign = (int*)alloc((size_t)NB * NP * 4);
  int* rowminArr = (int*)alloc((size_t)NB * NP * 4);
  int* colcnt = (int*)alloc((size_t)NB * NG * 4);
  int* wlist = (int*)alloc((size_t)NB * NP * 4);
  int* wcount = (int*)alloc(256);

  int* out = (int*)d_out;
  dim3 blk(256);
  prep_gt_kernel<<<dim3(NB), dim3(128), 0, stream>>>(
      gt_boxes, gt_labels, gtaux, colcnt, wcount);
  prep_pred_kernel<<<dim3((NP + 255) / 256, NB), blk, 0, stream>>>(
      pred_logits, pred_boxes, gtaux, paux, clst, rowcnt, rowassign);
  stage1_kernel<<<dim3(NB * (NG / CPB) * NCH), blk, 0, stream>>>(
      paux, clst, gtaux, iou5, ck);
  stage2_kernel<<<dim3((NB * NG + 255) / 256), blk, 0, stream>>>(
      iou5, ck, head, colsel, rowcnt, rowassign, wlist, wcount);
  epi_kernel<<<dim3(EPIW + 8), blk, 0, stream>>>(
      paux, clst, gtaux, colsel, rowcnt, wlist, wcount, rowminArr, colcnt);
  fixup_kernel<<<dim3(NG, NB), blk, 0, stream>>>(
      paux, clst, gtaux, colcnt, rowcnt, rowassign);
  output_kernel<<<dim3(((int)NBPs + 255) / 256), blk, 0, stream>>>(
      rowcnt, rowassign, rowminArr, out);
}

// Round 9
// 123.180 us; speedup vs baseline: 1.5224x; 1.1028x over previous
//
#include <hip/hip_runtime.h>
#include <stdint.h>
#include <math.h>

#define NB 16
#define NP 6000
#define NG 128
#define NC 10
#define SELMAX 4     // dyn = int(sum(top5 iou) - 0.5) <= int(4.5) = 4, provable
#define GSTR 24      // padded per-GT stride
#define PCH 2048     // preds per stage1 chunk
#define NCH 3        // chunks (3*2048 >= 6000)
#define CPB 2        // columns per stage1 block
#define QITER 32     // PCH/64 elements per extraction lane
#define EPIW 128     // worklist blocks in epi_kernel (512 waves)

typedef unsigned long long u64;
#define NBPs ((size_t)NB * NP)

__device__ __forceinline__ uint32_t fkey(float f) {
  // monotone float->uint mapping for lexicographic ordering
  uint32_t u = __float_as_uint(f);
  return (u & 0x80000000u) ? ~u : (u | 0x80000000u);
}
__device__ __forceinline__ float fkey_inv(uint32_t k) {
  uint32_t u = (k & 0x80000000u) ? (k & 0x7fffffffu) : ~k;
  return __uint_as_float(u);
}
__device__ __forceinline__ u64 shfl_xor_u64(u64 v, int m) {
  uint32_t lo = (uint32_t)v, hi = (uint32_t)(v >> 32);
  lo = (uint32_t)__shfl_xor((int)lo, m, 64);
  hi = (uint32_t)__shfl_xor((int)hi, m, 64);
  return ((u64)hi << 32) | lo;
}
// 256-thread block min-reduce (used only by rare-path fixup)
__device__ __forceinline__ u64 block_min_u64(u64 v, u64* sred, int lane, int wid) {
  for (int o = 1; o < 64; o <<= 1) {
    u64 t = shfl_xor_u64(v, o);
    if (t < v) v = t;
  }
  __syncthreads();
  if (lane == 0) sred[wid] = v;
  __syncthreads();
  u64 r = sred[0];
  if (sred[1] < r) r = sred[1];
  if (sred[2] < r) r = sred[2];
  if (sred[3] < r) r = sred[3];
  return r;
}

// ---------------------------------------------------------------------------
// Fused prep: per-block shg computed directly from gt_boxes (no prep_gt
// dependency); block x==0 of each b additionally persists gtaux + zeroes
// colcnt/wcount.  Then per-pred focal table, box decode, valid, row inits.
__global__ __launch_bounds__(256) void prep_kernel(
    const float* __restrict__ gt_boxes,
    const int* __restrict__ gt_labels,
    const float* __restrict__ pred_logits,
    const float* __restrict__ pred_boxes,
    float* __restrict__ gtaux,
    float* __restrict__ paux,
    float* __restrict__ clst,
    int* __restrict__ rowcnt,
    int* __restrict__ rowassign,
    int* __restrict__ colcnt,
    int* __restrict__ wcount) {
#pragma clang fp contract(off)
  __shared__ float shg[NG * 12];
  const int b = blockIdx.y, tid = threadIdx.x;
  if (tid < NG) {
    const int g = tid;
    const float* gb = gt_boxes + ((size_t)b * NG + g) * 7;
    float cx = gb[0], cy = gb[1], cz = gb[2];
    float dx = gb[3], dy = gb[4], dz = gb[5];
    float yaw = gb[6];
    float cyw = cosf(yaw), syw = sinf(yaw);
    float ca = fabsf(cyw), sa = fabsf(syw);
    float hx = 0.5f * (dx * ca + dy * sa);
    float hy = 0.5f * (dx * sa + dy * ca);
    float hz = 0.5f * dz;
    float gmin0 = cx - hx, gmin1 = cy - hy, gmin2 = cz - hz;
    float gmax0 = cx + hx, gmax1 = cy + hy, gmax2 = cz + hz;
    float* s = &shg[g * 12];
    s[0] = gmin0; s[1] = gmin1; s[2] = gmin2;
    s[3] = gmax0; s[4] = gmax1; s[5] = gmax2;
    s[6] = cx - 1.5f * dx; s[7] = cy - 1.5f * dy; s[8] = cz - 1.5f * dz;
    s[9] = cx + 1.5f * dx; s[10] = cy + 1.5f * dy; s[11] = cz + 1.5f * dz;
    if (blockIdx.x == 0) {
      float vg = ((gmax0 - gmin0) * (gmax1 - gmin1)) * (gmax2 - gmin2);
      float* o = gtaux + ((size_t)b * NG + g) * GSTR;
      o[0] = gmin0; o[1] = gmin1; o[2] = gmin2;
      o[3] = gmax0; o[4] = gmax1; o[5] = gmax2;
      o[6] = s[6]; o[7] = s[7]; o[8] = s[8];
      o[9] = s[9]; o[10] = s[10]; o[11] = s[11];
      o[12] = cx; o[13] = cy; o[14] = cz;
      o[15] = logf(dx); o[16] = logf(dy); o[17] = logf(dz);
      o[18] = syw; o[19] = cyw;
      o[20] = vg;
      o[21] = __int_as_float(gt_labels[(size_t)b * NG + g]);
      o[22] = 0.0f; o[23] = 0.0f;
      colcnt[b * NG + g] = 0;
      if (b == 0 && g == 0) wcount[0] = 0;
    }
  }
  __syncthreads();
  const int p = blockIdx.x * 256 + tid;
  if (p >= NP) return;
  const size_t idx = (size_t)b * NP + p;
  const float* lg = pred_logits + idx * NC;
  for (int c = 0; c < NC; ++c) {
    float x = lg[c];
    float pr = 1.0f / (1.0f + expf(-x));
    float neg = (-logf(1.0f - pr + 1e-12f) * 0.75f) * (pr * pr);
    float pos = (-logf(pr + 1e-12f) * 0.25f) * ((1.0f - pr) * (1.0f - pr));
    clst[(size_t)c * NBPs + idx] = (pos - neg) * 2.0f;
  }
  const float* bx = pred_boxes + idx * 10;
  float b0 = bx[0], b1 = bx[1], b2 = bx[2], b3 = bx[3], b4 = bx[4];
  float b5 = bx[5], b6 = bx[6], b7 = bx[7];
  float yaw = atan2f(b6, b7);
  float d0 = expf(b3), d1 = expf(b4), d2 = expf(b5);
  float ca = fabsf(cosf(yaw)), sa = fabsf(sinf(yaw));
  float hx = 0.5f * (d0 * ca + d1 * sa);
  float hy = 0.5f * (d0 * sa + d1 * ca);
  float hz = 0.5f * d2;
  float pmin0 = b0 - hx, pmin1 = b1 - hy, pmin2 = b2 - hz;
  float pmax0 = b0 + hx, pmax1 = b1 + hy, pmax2 = b2 + hz;
  int valid = 0;
  for (int g = 0; g < NG; ++g) {
    const float* s = &shg[g * 12];
    bool inb = (b0 > s[0]) && (b0 < s[3]) && (b1 > s[1]) && (b1 < s[4]) &&
               (b2 > s[2]) && (b2 < s[5]);
    bool inc = (b0 > s[6]) && (b0 < s[9]) && (b1 > s[7]) && (b1 < s[10]) &&
               (b2 > s[8]) && (b2 < s[11]);
    if (inb || inc) { valid = 1; break; }
  }
  float* o = paux + idx * 16;
  o[0] = b0; o[1] = b1; o[2] = b2; o[3] = b3;
  o[4] = b4; o[5] = b5; o[6] = b6; o[7] = b7;
  o[8] = pmin0; o[9] = pmin1; o[10] = pmin2;
  o[11] = pmax0; o[12] = pmax1; o[13] = pmax2;
  o[14] = ((pmax0 - pmin0) * (pmax1 - pmin1)) * (pmax2 - pmin2);
  o[15] = valid ? 0.0f : 10000.0f;        // pen, added after base cost
  rowcnt[idx] = 0;
  rowassign[idx] = 0x7fffffff;
}

// Per-column GT parameters.
struct GTp {
  float gmin0, gmin1, gmin2, gmax0, gmax1, gmax2;
  float lo0, lo1, lo2, hi0, hi1, hi2;
  float gtn0, gtn1, gtn2, gtn3, gtn4, gtn5, gtn6, gtn7;
  float vg;
  int label;
};
__device__ __forceinline__ GTp load_gt(const float* __restrict__ gtaux,
                                       int b, int g) {
  const float* ga = gtaux + ((size_t)b * NG + g) * GSTR;
  GTp t;
  t.gmin0 = ga[0]; t.gmin1 = ga[1]; t.gmin2 = ga[2];
  t.gmax0 = ga[3]; t.gmax1 = ga[4]; t.gmax2 = ga[5];
  t.lo0 = ga[6]; t.lo1 = ga[7]; t.lo2 = ga[8];
  t.hi0 = ga[9]; t.hi1 = ga[10]; t.hi2 = ga[11];
  t.gtn0 = ga[12]; t.gtn1 = ga[13]; t.gtn2 = ga[14]; t.gtn3 = ga[15];
  t.gtn4 = ga[16]; t.gtn5 = ga[17]; t.gtn6 = ga[18]; t.gtn7 = ga[19];
  t.vg = ga[20];
  t.label = __float_as_int(ga[21]);
  return t;
}

// Exact reference arithmetic (same op order as all passing rounds); caller
// adds the row-uniform pen last, exactly as the reference does.
__device__ __forceinline__ float cost_base(
    float b0, float b1, float b2, float b3, float b4, float b5, float b6,
    float b7, float pmin0, float pmin1, float pmin2, float pmax0, float pmax1,
    float pmax2, float vp, float cls, const GTp& t, float* iou_out) {
#pragma clang fp contract(off)
  float r = fabsf(b0 - t.gtn0);
  r = r + fabsf(b1 - t.gtn1);
  r = r + fabsf(b2 - t.gtn2);
  r = r + fabsf(b3 - t.gtn3);
  r = r + fabsf(b4 - t.gtn4);
  r = r + fabsf(b5 - t.gtn5);
  r = r + fabsf(b6 - t.gtn6);
  r = r + fabsf(b7 - t.gtn7);
  float reg = r * 0.25f;
  float li0 = fmaxf(pmin0, t.gmin0), li1 = fmaxf(pmin1, t.gmin1),
        li2 = fmaxf(pmin2, t.gmin2);
  float hj0 = fminf(pmax0, t.gmax0), hj1 = fminf(pmax1, t.gmax1),
        hj2 = fminf(pmax2, t.gmax2);
  float e0 = fmaxf(hj0 - li0, 0.0f), e1 = fmaxf(hj1 - li1, 0.0f),
        e2 = fmaxf(hj2 - li2, 0.0f);
  float inter = (e0 * e1) * e2;
  float iou = inter / (((vp + t.vg) - inter) + 1e-7f);
  bool inb = (b0 > t.gmin0) && (b0 < t.gmax0) && (b1 > t.gmin1) &&
             (b1 < t.gmax1) && (b2 > t.gmin2) && (b2 < t.gmax2);
  bool inc = (b0 > t.lo0) && (b0 < t.hi0) && (b1 > t.lo1) && (b1 < t.hi1) &&
             (b2 > t.lo2) && (b2 < t.hi2);
  *iou_out = iou;
  return ((cls + reg) + (-(iou * 0.25f))) + ((inb && inc) ? 0.0f : 100.0f);
}

// ---------------------------------------------------------------------------
// Stage 1: per (chunk, g-pair, b) block.  Costs/ious computed on the fly,
// fkeys staged in LDS; extraction = per-lane streaming top-k into sorted
// register lists (single LDS pass) + k knockout shfl rounds.  Wave w ->
// column (w>>1), metric (w&1).  Emits per-chunk top-5 iou values and top-4
// (cost,p) keys.
__global__ __launch_bounds__(256) void stage1_kernel(
    const float* __restrict__ paux,
    const float* __restrict__ clst,
    const float* __restrict__ gtaux,
    float* __restrict__ iou5,
    u64* __restrict__ ck) {
#pragma clang fp contract(off)
  const int n = blockIdx.x;                   // 3072 = 8 * 384
  const int orig = (n & 7) * 384 + (n >> 3);  // XCD x -> b in {2x, 2x+1}
  const int b = orig / 192;
  const int rem = orig - b * 192;
  const int gq = rem / NCH;
  const int ch = rem - gq * NCH;
  const int g0 = gq * CPB;
  const int tid = threadIdx.x;
  const int lane = tid & 63, wid = tid >> 6;

  __shared__ uint32_t kiouL[CPB][PCH];        // 16 KB
  __shared__ uint32_t kcostL[CPB][PCH];       // 16 KB

  GTp t0 = load_gt(gtaux, b, g0);
  GTp t1 = load_gt(gtaux, b, g0 + 1);
  const size_t rowbase = (size_t)b * NP;
  const uint32_t PAD_I = fkey(-INFINITY);
  const uint32_t PAD_C = fkey(INFINITY);

  for (int j = 0; j < PCH / 256; ++j) {
    const int pl = j * 256 + tid;             // LDS write: stride-1, no conflict
    const int p = ch * PCH + pl;
    uint32_t ki0 = PAD_I, ki1 = PAD_I, kc0 = PAD_C, kc1 = PAD_C;
    if (p < NP) {
      const size_t idx = rowbase + p;
      const float4* pa = (const float4*)(paux + idx * 16);
      float4 A = pa[0], B = pa[1], C = pa[2], D = pa[3];
      float cls0 = clst[(size_t)t0.label * NBPs + idx];
      float cls1 = clst[(size_t)t1.label * NBPs + idx];
      float iou0, iou1;
      float c0 = cost_base(A.x, A.y, A.z, A.w, B.x, B.y, B.z, B.w,
                           C.x, C.y, C.z, C.w, D.x, D.y, D.z,
                           cls0, t0, &iou0);
      float c1 = cost_base(A.x, A.y, A.z, A.w, B.x, B.y, B.z, B.w,
                           C.x, C.y, C.z, C.w, D.x, D.y, D.z,
                           cls1, t1, &iou1);
      ki0 = fkey(iou0); kc0 = fkey(c0 + D.w);
      ki1 = fkey(iou1); kc1 = fkey(c1 + D.w);
    }
    kiouL[0][pl] = ki0;
    kiouL[1][pl] = ki1;
    kcostL[0][pl] = kc0;
    kcostL[1][pl] = kc1;
  }
  __syncthreads();

  const int c = wid >> 1;
  const int col = b * NG + g0 + c;
  const unsigned gbase = (unsigned)(ch * PCH);

  if ((wid & 1) == 0) {
    // ---- iou top-5: per-lane sorted top-5 (u32 desc; real keys >= 0x80000000
    // so 0 is a safe -inf sentinel), then 5 knockout rounds on (key,lane).
    uint32_t a0 = 0, a1 = 0, a2 = 0, a3 = 0, a4 = 0;
    for (int q = 0; q < QITER; ++q) {
      uint32_t k = kiouL[c][q * 64 + lane];   // stride-1 across lanes
      if (k > a4) {
        a4 = k;
        if (a4 > a3) { uint32_t t = a4; a4 = a3; a3 = t; }
        if (a3 > a2) { uint32_t t = a3; a3 = a2; a2 = t; }
        if (a2 > a1) { uint32_t t = a2; a2 = a1; a1 = t; }
        if (a1 > a0) { uint32_t t = a1; a1 = a0; a0 = t; }
      }
    }
    int hp = 0;
    for (int k = 0; k < 5; ++k) {
      uint32_t cand = (hp == 0) ? a0 : (hp == 1) ? a1 : (hp == 2) ? a2
                    : (hp == 3) ? a3 : (hp == 4) ? a4 : 0u;
      u64 key = ((u64)cand << 32) | (unsigned)lane;
      u64 r = key;
      for (int o = 1; o < 64; o <<= 1) {
        u64 t = shfl_xor_u64(r, o);
        if (t > r) r = t;
      }
      if (lane == 0)
        iou5[(size_t)col * 16 + ch * 5 + k] = fkey_inv((uint32_t)(r >> 32));
      if (r == key) hp++;                     // unique winner advances
    }
  } else {
    // ---- cost top-4: per-lane sorted top-4 of u64 (fkey, p) asc, then 4
    // knockout min rounds (keys unique -> stable rank order).
    u64 c0 = ~0ull, c1 = ~0ull, c2 = ~0ull, c3 = ~0ull;
    for (int q = 0; q < QITER; ++q) {
      const int pl = q * 64 + lane;
      u64 key = ((u64)kcostL[c][pl] << 32) | (u64)(gbase + (unsigned)pl);
      if (key < c3) {
        c3 = key;
        if (c3 < c2) { u64 t = c3; c3 = c2; c2 = t; }
        if (c2 < c1) { u64 t = c2; c2 = c1; c1 = t; }
        if (c1 < c0) { u64 t = c1; c1 = c0; c0 = t; }
      }
    }
    int hp = 0;
    for (int k = 0; k < 4; ++k) {
      u64 cand = (hp == 0) ? c0 : (hp == 1) ? c1 : (hp == 2) ? c2
               : (hp == 3) ? c3 : ~0ull;
      u64 r = cand;
      for (int o = 1; o < 64; o <<= 1) {
        u64 t = shfl_xor_u64(r, o);
        if (t < r) r = t;
      }
      if (lane == 0) ck[(size_t)col * 16 + ch * 4 + k] = r;
      if (r == cand) hp++;
    }
  }
}

// ---------------------------------------------------------------------------
// Stage 2: one thread per column.  Merge 3 chunks: global top-5 iou (desc,
// left-assoc sum) -> dyn; global top-dyn (cost,p) keys (stable asc) ->
// colsel + rowcnt/rowassign atomics.  Rows crossing rowcnt 1->2 enqueue
// exactly once into the prior-row worklist.
__global__ __launch_bounds__(256) void stage2_kernel(
    const float* __restrict__ iou5,
    const u64* __restrict__ ck,
    const int* __restrict__ head_ptr,
    int* __restrict__ colsel,
    int* __restrict__ rowcnt,
    int* __restrict__ rowassign,
    int* __restrict__ wlist,
    int* __restrict__ wcount) {
#pragma clang fp contract(off)
  const int col = blockIdx.x * 256 + threadIdx.x;
  if (col >= NB * NG) return;
  const int b = col / NG, g = col - b * NG;
  const float* ip = iou5 + (size_t)col * 16;
  float m0 = -INFINITY, m1 = -INFINITY, m2 = -INFINITY, m3 = -INFINITY,
        m4 = -INFINITY;
  for (int i = 0; i < 5 * NCH; ++i) {
    float v = ip[i];
    if (v > m4) {
      m4 = v;
      if (m4 > m3) { float t = m4; m4 = m3; m3 = t; }
      if (m3 > m2) { float t = m3; m3 = m2; m2 = t; }
      if (m2 > m1) { float t = m2; m2 = m1; m1 = t; }
      if (m1 > m0) { float t = m1; m1 = m0; m0 = t; }
    }
  }
  float sum5 = ((((m0 + m1) + m2) + m3) + m4);   // desc-order left-assoc
  float adj = sum5 - 0.5f * (float)(6 - head_ptr[0]);
  int dyn = (int)adj;                // trunc toward zero == astype(int32)
  if (dyn < 1) dyn = 1;
  if (dyn > SELMAX) dyn = SELMAX;

  const u64* kp = ck + (size_t)col * 16;
  u64 s0 = ~0ull, s1 = ~0ull, s2 = ~0ull, s3 = ~0ull;
  for (int i = 0; i < SELMAX * NCH; ++i) {
    u64 k = kp[i];
    if (k < s3) {
      s3 = k;
      if (s3 < s2) { u64 t = s3; s3 = s2; s2 = t; }
      if (s2 < s1) { u64 t = s2; s2 = s1; s1 = t; }
      if (s1 < s0) { u64 t = s1; s1 = s0; s0 = t; }
    }
  }
  const size_t rowbase = (size_t)b * NP;
  int pk[4];
  pk[0] = (int)(s0 & 0xffffffffu);
  pk[1] = (int)(s1 & 0xffffffffu);
  pk[2] = (int)(s2 & 0xffffffffu);
  pk[3] = (int)(s3 & 0xffffffffu);
  for (int k = 0; k < SELMAX; ++k) {
    int sel = (k < dyn) ? pk[k] : -1;
    colsel[(size_t)col * SELMAX + k] = sel;
    if (sel >= 0) {
      int old = atomicAdd(&rowcnt[rowbase + sel], 1);
      if (old == 1) {
        int slot = atomicAdd(wcount, 1);
        wlist[slot] = (int)(rowbase + sel);
      }
      atomicMin(&rowassign[rowbase + sel], g);
    }
  }
}

// ---------------------------------------------------------------------------
// Epilogue: blocks [0,EPIW): one WAVE per prior row from the worklist —
// 128 g's spread 2-per-lane, parallel gathers, u64-key min reduce (key
// includes g -> first-g tiebreak).  Blocks [EPIW, EPIW+8): colcnt part (a).
__global__ __launch_bounds__(256) void epi_kernel(
    const float* __restrict__ paux,
    const float* __restrict__ clst,
    const float* __restrict__ gtaux,
    const int* __restrict__ colsel,
    const int* __restrict__ rowcnt,
    const int* __restrict__ wlist,
    const int* __restrict__ wcount,
    int* __restrict__ rowminArr,
    int* __restrict__ colcnt) {
#pragma clang fp contract(off)
  const int tid = threadIdx.x;
  if (blockIdx.x >= EPIW) {
    // colcnt part (a): selections whose row stayed single (rowcnt==1)
    const int col = (blockIdx.x - EPIW) * 256 + tid;
    if (col < NB * NG) {
      const int b = col / NG;
      int cnt = 0;
      const size_t cb = (size_t)col * SELMAX;
      for (int k = 0; k < SELMAX; ++k) {
        int s = colsel[cb + k];
        if (s >= 0 && rowcnt[(size_t)b * NP + s] == 1) cnt++;
      }
      if (cnt) atomicAdd(&colcnt[col], cnt);
    }
    return;
  }
  const int lane = tid & 63, wid = tid >> 6;
  const int wavesTotal = EPIW * 4;
  const int wave = blockIdx.x * 4 + wid;
  const int n = wcount[0];
  for (int e = wave; e < n; e += wavesTotal) {
    const int idx = wlist[e];
    const int b = idx / NP;
    const float4* pa = (const float4*)(paux + (size_t)idx * 16);
    float4 A = pa[0], Bq = pa[1], Cq = pa[2], Dq = pa[3];
    const float pen = Dq.w;
    u64 best = ~0ull;
    for (int h = 0; h < 2; ++h) {
      const int g = h * 64 + lane;
      GTp t = load_gt(gtaux, b, g);
      float cls = clst[(size_t)t.label * NBPs + idx];
      float iou;
      float cc = cost_base(A.x, A.y, A.z, A.w, Bq.x, Bq.y, Bq.z, Bq.w,
                           Cq.x, Cq.y, Cq.z, Cq.w, Dq.x, Dq.y, Dq.z,
                           cls, t, &iou);
      u64 key = ((u64)fkey(cc + pen) << 32) | (unsigned)g;
      if (key < best) best = key;
    }
    for (int o = 1; o < 64; o <<= 1) {
      u64 t = shfl_xor_u64(best, o);
      if (t < best) best = t;
    }
    if (lane == 0) {
      const int bg = (int)(best & 0xffffffffu);
      rowminArr[idx] = bg;
      atomicAdd(&colcnt[b * NG + bg], 1);
    }
  }
}

// Empty columns: recompute costs over never-matched rows, argmin (cost+pen,p).
__global__ __launch_bounds__(256) void fixup_kernel(
    const float* __restrict__ paux,
    const float* __restrict__ clst,
    const float* __restrict__ gtaux,
    const int* __restrict__ colcnt,
    const int* __restrict__ rowcnt,
    int* __restrict__ rowassign) {
#pragma clang fp contract(off)
  const int g = blockIdx.x, b = blockIdx.y, tid = threadIdx.x;
  if (colcnt[b * NG + g] != 0) return;  // uniform across block
  const int lane = tid & 63, wid = tid >> 6;
  const size_t rowbase = (size_t)b * NP;
  GTp t = load_gt(gtaux, b, g);
  u64 best = ~0ull;
  for (int p = tid; p < NP; p += 256) {
    const size_t idx = rowbase + p;
    if (rowcnt[idx] == 0) {
      const float4* pa = (const float4*)(paux + idx * 16);
      float4 A = pa[0], Bq = pa[1], Cq = pa[2], Dq = pa[3];
      float cls = clst[(size_t)t.label * NBPs + idx];
      float iou;
      float cc = cost_base(A.x, A.y, A.z, A.w, Bq.x, Bq.y, Bq.z, Bq.w,
                           Cq.x, Cq.y, Cq.z, Cq.w, Dq.x, Dq.y, Dq.z,
                           cls, t, &iou);
      u64 key = ((u64)fkey(cc + Dq.w) << 32) | (unsigned)p;
      if (key < best) best = key;
    }
  }
  __shared__ u64 sred[4];
  u64 rr = block_min_u64(best, sred, lane, wid);
  if (tid == 0) {
    int pos = (int)(rr & 0xffffffffu);
    atomicMin(&rowassign[rowbase + pos], g);  // min g == argmax first-1
  }
}

__global__ void output_kernel(const int* __restrict__ rowcnt,
                              const int* __restrict__ rowassign,
                              const int* __restrict__ rowminArr,
                              int* __restrict__ out) {
  const int i = blockIdx.x * 256 + threadIdx.x;
  if (i >= (int)NBPs) return;
  int rc = rowcnt[i];
  int fg, m;
  if (rc == 0) {
    int ra = rowassign[i];
    if (ra == 0x7fffffff) { fg = 0; m = -1; }
    else { fg = 1; m = ra; }          // fixup-assigned (min g)
  } else if (rc == 1) {
    fg = 1; m = rowassign[i];         // single selecting column
  } else {
    fg = 1; m = rowminArr[i];         // prior row -> one-hot at row argmin
  }
  out[i] = fg;
  out[NBPs + i] = m;
}

// ---------------------------------------------------------------------------
extern "C" void kernel_launch(void* const* d_in, const int* in_sizes, int n_in,
                              void* d_out, int out_size, void* d_ws, size_t ws_size,
                              hipStream_t stream) {
  const float* pred_logits = (const float*)d_in[0];
  const float* pred_boxes = (const float*)d_in[1];
  const float* gt_boxes = (const float*)d_in[2];
  const int* gt_labels = (const int*)d_in[3];
  const int* head = (const int*)d_in[4];
  (void)in_sizes; (void)n_in; (void)out_size; (void)ws_size;

  char* w = (char*)d_ws;
  size_t off = 0;
  auto alloc = [&](size_t bytes) -> void* {
    void* p = w + off;
    off += (bytes + 255) & ~(size_t)255;
    return p;
  };
  float* paux = (float*)alloc((size_t)NB * NP * 16 * 4);       // 6.1 MB
  float* clst = (float*)alloc((size_t)NC * NB * NP * 4);       // 3.8 MB
  float* gtaux = (float*)alloc((size_t)NB * NG * GSTR * 4);
  float* iou5 = (float*)alloc((size_t)NB * NG * 16 * 4);       // 128 KB
  u64* ck = (u64*)alloc((size_t)NB * NG * 16 * 8);             // 256 KB
  int* colsel = (int*)alloc((size_t)NB * NG * SELMAX * 4);
  int* rowcnt = (int*)alloc((size_t)NB * NP * 4);
  int* rowassign = (int*)alloc((size_t)NB * NP * 4);
  int* rowminArr = (int*)alloc((size_t)NB * NP * 4);
  int* colcnt = (int*)alloc((size_t)NB * NG * 4);
  int* wlist = (int*)alloc((size_t)NB * NP * 4);
  int* wcount = (int*)alloc(256);

  int* out = (int*)d_out;
  dim3 blk(256);
  prep_kernel<<<dim3((NP + 255) / 256, NB), blk, 0, stream>>>(
      gt_boxes, gt_labels, pred_logits, pred_boxes, gtaux, paux, clst,
      rowcnt, rowassign, colcnt, wcount);
  stage1_kernel<<<dim3(NB * (NG / CPB) * NCH), blk, 0, stream>>>(
      paux, clst, gtaux, iou5, ck);
  stage2_kernel<<<dim3((NB * NG + 255) / 256), blk, 0, stream>>>(
      iou5, ck, head, colsel, rowcnt, rowassign, wlist, wcount);
  epi_kernel<<<dim3(EPIW + 8), blk, 0, stream>>>(
      paux, clst, gtaux, colsel, rowcnt, wlist, wcount, rowminArr, colcnt);
  fixup_kernel<<<dim3(NG, NB), blk, 0, stream>>>(
      paux, clst, gtaux, colcnt, rowcnt, rowassign);
  output_kernel<<<dim3(((int)NBPs + 255) / 256), blk, 0, stream>>>(
      rowcnt, rowassign, rowminArr, out);
}

// Round 10
// 117.199 us; speedup vs baseline: 1.6000x; 1.0510x over previous
//
#include <hip/hip_runtime.h>
#include <stdint.h>
#include <math.h>

#define NB 16
#define NP 6000
#define NG 128
#define NC 10
#define SELMAX 4     // dyn = int(sum(top5 iou) - 0.5) <= int(4.5) = 4, provable
#define GSTR 24      // padded per-GT stride
#define CPB 2        // columns per stage1 block
#define QN 24        // 24*256 >= NP
#define EPIW 128     // worklist blocks in epi_kernel (512 waves)

typedef unsigned long long u64;
#define NBPs ((size_t)NB * NP)

__device__ __forceinline__ uint32_t fkey(float f) {
  // monotone float->uint mapping for lexicographic ordering
  uint32_t u = __float_as_uint(f);
  return (u & 0x80000000u) ? ~u : (u | 0x80000000u);
}
__device__ __forceinline__ float fkey_inv(uint32_t k) {
  uint32_t u = (k & 0x80000000u) ? (k & 0x7fffffffu) : ~k;
  return __uint_as_float(u);
}
__device__ __forceinline__ u64 shfl_xor_u64(u64 v, int m) {
  uint32_t lo = (uint32_t)v, hi = (uint32_t)(v >> 32);
  lo = (uint32_t)__shfl_xor((int)lo, m, 64);
  hi = (uint32_t)__shfl_xor((int)hi, m, 64);
  return ((u64)hi << 32) | lo;
}
// 256-thread block min-reduce (used only by rare-path fixup)
__device__ __forceinline__ u64 block_min_u64(u64 v, u64* sred, int lane, int wid) {
  for (int o = 1; o < 64; o <<= 1) {
    u64 t = shfl_xor_u64(v, o);
    if (t < v) v = t;
  }
  __syncthreads();
  if (lane == 0) sred[wid] = v;
  __syncthreads();
  u64 r = sred[0];
  if (sred[1] < r) r = sred[1];
  if (sred[2] < r) r = sred[2];
  if (sred[3] < r) r = sred[3];
  return r;
}

// per-lane sorted insert: top-5 descending (u32), sentinel 0
__device__ __forceinline__ void ins5max(uint32_t& a0, uint32_t& a1, uint32_t& a2,
                                        uint32_t& a3, uint32_t& a4, uint32_t k) {
  if (k > a4) {
    a4 = k;
    if (a4 > a3) { uint32_t t = a4; a4 = a3; a3 = t; }
    if (a3 > a2) { uint32_t t = a3; a3 = a2; a2 = t; }
    if (a2 > a1) { uint32_t t = a2; a2 = a1; a1 = t; }
    if (a1 > a0) { uint32_t t = a1; a1 = a0; a0 = t; }
  }
}
// per-lane sorted insert: top-4 ascending (u64), sentinel ~0
__device__ __forceinline__ void ins4min(u64& c0, u64& c1, u64& c2, u64& c3, u64 k) {
  if (k < c3) {
    c3 = k;
    if (c3 < c2) { u64 t = c3; c3 = c2; c2 = t; }
    if (c2 < c1) { u64 t = c2; c2 = c1; c1 = t; }
    if (c1 < c0) { u64 t = c1; c1 = c0; c0 = t; }
  }
}
// wave knockout: extract top-5 values (desc) from per-lane sorted lists;
// lane 0 writes 5 floats to dst (LDS).  (key,lane) unique -> one hp advance.
__device__ __forceinline__ void wave_top5_iou(uint32_t a0, uint32_t a1,
                                              uint32_t a2, uint32_t a3,
                                              uint32_t a4, int lane,
                                              float* dst) {
  int hp = 0;
  for (int k = 0; k < 5; ++k) {
    uint32_t cand = (hp == 0) ? a0 : (hp == 1) ? a1 : (hp == 2) ? a2
                  : (hp == 3) ? a3 : (hp == 4) ? a4 : 0u;
    u64 key = ((u64)cand << 32) | (unsigned)lane;
    u64 r = key;
    for (int o = 1; o < 64; o <<= 1) {
      u64 t = shfl_xor_u64(r, o);
      if (t > r) r = t;
    }
    if (lane == 0) dst[k] = fkey_inv((uint32_t)(r >> 32));
    if (r == key) hp++;
  }
}
// wave knockout: extract 4 smallest unique u64 (fkey,p) keys; lane 0 writes.
__device__ __forceinline__ void wave_top4_cost(u64 c0, u64 c1, u64 c2, u64 c3,
                                               int lane, u64* dst) {
  int hp = 0;
  for (int k = 0; k < 4; ++k) {
    u64 cand = (hp == 0) ? c0 : (hp == 1) ? c1 : (hp == 2) ? c2
             : (hp == 3) ? c3 : ~0ull;
    u64 r = cand;
    for (int o = 1; o < 64; o <<= 1) {
      u64 t = shfl_xor_u64(r, o);
      if (t < r) r = t;
    }
    if (lane == 0) dst[k] = r;
    if (r == cand) hp++;
  }
}

// ---------------------------------------------------------------------------
// Fused prep: per-block shg computed directly from gt_boxes; block x==0 of
// each b persists gtaux + zeroes colcnt/wcount.  Then per-pred focal table,
// box decode, valid, row inits.
__global__ __launch_bounds__(256) void prep_kernel(
    const float* __restrict__ gt_boxes,
    const int* __restrict__ gt_labels,
    const float* __restrict__ pred_logits,
    const float* __restrict__ pred_boxes,
    float* __restrict__ gtaux,
    float* __restrict__ paux,
    float* __restrict__ clst,
    int* __restrict__ rowcnt,
    int* __restrict__ rowassign,
    int* __restrict__ colcnt,
    int* __restrict__ wcount) {
#pragma clang fp contract(off)
  __shared__ float shg[NG * 12];
  const int b = blockIdx.y, tid = threadIdx.x;
  if (tid < NG) {
    const int g = tid;
    const float* gb = gt_boxes + ((size_t)b * NG + g) * 7;
    float cx = gb[0], cy = gb[1], cz = gb[2];
    float dx = gb[3], dy = gb[4], dz = gb[5];
    float yaw = gb[6];
    float cyw = cosf(yaw), syw = sinf(yaw);
    float ca = fabsf(cyw), sa = fabsf(syw);
    float hx = 0.5f * (dx * ca + dy * sa);
    float hy = 0.5f * (dx * sa + dy * ca);
    float hz = 0.5f * dz;
    float gmin0 = cx - hx, gmin1 = cy - hy, gmin2 = cz - hz;
    float gmax0 = cx + hx, gmax1 = cy + hy, gmax2 = cz + hz;
    float* s = &shg[g * 12];
    s[0] = gmin0; s[1] = gmin1; s[2] = gmin2;
    s[3] = gmax0; s[4] = gmax1; s[5] = gmax2;
    s[6] = cx - 1.5f * dx; s[7] = cy - 1.5f * dy; s[8] = cz - 1.5f * dz;
    s[9] = cx + 1.5f * dx; s[10] = cy + 1.5f * dy; s[11] = cz + 1.5f * dz;
    if (blockIdx.x == 0) {
      float vg = ((gmax0 - gmin0) * (gmax1 - gmin1)) * (gmax2 - gmin2);
      float* o = gtaux + ((size_t)b * NG + g) * GSTR;
      o[0] = gmin0; o[1] = gmin1; o[2] = gmin2;
      o[3] = gmax0; o[4] = gmax1; o[5] = gmax2;
      o[6] = s[6]; o[7] = s[7]; o[8] = s[8];
      o[9] = s[9]; o[10] = s[10]; o[11] = s[11];
      o[12] = cx; o[13] = cy; o[14] = cz;
      o[15] = logf(dx); o[16] = logf(dy); o[17] = logf(dz);
      o[18] = syw; o[19] = cyw;
      o[20] = vg;
      o[21] = __int_as_float(gt_labels[(size_t)b * NG + g]);
      o[22] = 0.0f; o[23] = 0.0f;
      colcnt[b * NG + g] = 0;
      if (b == 0 && g == 0) wcount[0] = 0;
    }
  }
  __syncthreads();
  const int p = blockIdx.x * 256 + tid;
  if (p >= NP) return;
  const size_t idx = (size_t)b * NP + p;
  const float* lg = pred_logits + idx * NC;
  for (int c = 0; c < NC; ++c) {
    float x = lg[c];
    float pr = 1.0f / (1.0f + expf(-x));
    float neg = (-logf(1.0f - pr + 1e-12f) * 0.75f) * (pr * pr);
    float pos = (-logf(pr + 1e-12f) * 0.25f) * ((1.0f - pr) * (1.0f - pr));
    clst[(size_t)c * NBPs + idx] = (pos - neg) * 2.0f;
  }
  const float* bx = pred_boxes + idx * 10;
  float b0 = bx[0], b1 = bx[1], b2 = bx[2], b3 = bx[3], b4 = bx[4];
  float b5 = bx[5], b6 = bx[6], b7 = bx[7];
  float yaw = atan2f(b6, b7);
  float d0 = expf(b3), d1 = expf(b4), d2 = expf(b5);
  float ca = fabsf(cosf(yaw)), sa = fabsf(sinf(yaw));
  float hx = 0.5f * (d0 * ca + d1 * sa);
  float hy = 0.5f * (d0 * sa + d1 * ca);
  float hz = 0.5f * d2;
  float pmin0 = b0 - hx, pmin1 = b1 - hy, pmin2 = b2 - hz;
  float pmax0 = b0 + hx, pmax1 = b1 + hy, pmax2 = b2 + hz;
  int valid = 0;
  for (int g = 0; g < NG; ++g) {
    const float* s = &shg[g * 12];
    bool inb = (b0 > s[0]) && (b0 < s[3]) && (b1 > s[1]) && (b1 < s[4]) &&
               (b2 > s[2]) && (b2 < s[5]);
    bool inc = (b0 > s[6]) && (b0 < s[9]) && (b1 > s[7]) && (b1 < s[10]) &&
               (b2 > s[8]) && (b2 < s[11]);
    if (inb || inc) { valid = 1; break; }
  }
  float* o = paux + idx * 16;
  o[0] = b0; o[1] = b1; o[2] = b2; o[3] = b3;
  o[4] = b4; o[5] = b5; o[6] = b6; o[7] = b7;
  o[8] = pmin0; o[9] = pmin1; o[10] = pmin2;
  o[11] = pmax0; o[12] = pmax1; o[13] = pmax2;
  o[14] = ((pmax0 - pmin0) * (pmax1 - pmin1)) * (pmax2 - pmin2);
  o[15] = valid ? 0.0f : 10000.0f;        // pen, added after base cost
  rowcnt[idx] = 0;
  rowassign[idx] = 0x7fffffff;
}

// Per-column GT parameters (block-uniform -> SGPR loads).
struct GTp {
  float gmin0, gmin1, gmin2, gmax0, gmax1, gmax2;
  float lo0, lo1, lo2, hi0, hi1, hi2;
  float gtn0, gtn1, gtn2, gtn3, gtn4, gtn5, gtn6, gtn7;
  float vg;
  int label;
};
__device__ __forceinline__ GTp load_gt(const float* __restrict__ gtaux,
                                       int b, int g) {
  const float* ga = gtaux + ((size_t)b * NG + g) * GSTR;
  GTp t;
  t.gmin0 = ga[0]; t.gmin1 = ga[1]; t.gmin2 = ga[2];
  t.gmax0 = ga[3]; t.gmax1 = ga[4]; t.gmax2 = ga[5];
  t.lo0 = ga[6]; t.lo1 = ga[7]; t.lo2 = ga[8];
  t.hi0 = ga[9]; t.hi1 = ga[10]; t.hi2 = ga[11];
  t.gtn0 = ga[12]; t.gtn1 = ga[13]; t.gtn2 = ga[14]; t.gtn3 = ga[15];
  t.gtn4 = ga[16]; t.gtn5 = ga[17]; t.gtn6 = ga[18]; t.gtn7 = ga[19];
  t.vg = ga[20];
  t.label = __float_as_int(ga[21]);
  return t;
}

// Exact reference arithmetic (same op order as all passing rounds); caller
// adds the row-uniform pen last, exactly as the reference does.
__device__ __forceinline__ float cost_base(
    float b0, float b1, float b2, float b3, float b4, float b5, float b6,
    float b7, float pmin0, float pmin1, float pmin2, float pmax0, float pmax1,
    float pmax2, float vp, float cls, const GTp& t, float* iou_out) {
#pragma clang fp contract(off)
  float r = fabsf(b0 - t.gtn0);
  r = r + fabsf(b1 - t.gtn1);
  r = r + fabsf(b2 - t.gtn2);
  r = r + fabsf(b3 - t.gtn3);
  r = r + fabsf(b4 - t.gtn4);
  r = r + fabsf(b5 - t.gtn5);
  r = r + fabsf(b6 - t.gtn6);
  r = r + fabsf(b7 - t.gtn7);
  float reg = r * 0.25f;
  float li0 = fmaxf(pmin0, t.gmin0), li1 = fmaxf(pmin1, t.gmin1),
        li2 = fmaxf(pmin2, t.gmin2);
  float hj0 = fminf(pmax0, t.gmax0), hj1 = fminf(pmax1, t.gmax1),
        hj2 = fminf(pmax2, t.gmax2);
  float e0 = fmaxf(hj0 - li0, 0.0f), e1 = fmaxf(hj1 - li1, 0.0f),
        e2 = fmaxf(hj2 - li2, 0.0f);
  float inter = (e0 * e1) * e2;
  float iou = inter / (((vp + t.vg) - inter) + 1e-7f);
  bool inb = (b0 > t.gmin0) && (b0 < t.gmax0) && (b1 > t.gmin1) &&
             (b1 < t.gmax1) && (b2 > t.gmin2) && (b2 < t.gmax2);
  bool inc = (b0 > t.lo0) && (b0 < t.hi0) && (b1 > t.lo1) && (b1 < t.hi1) &&
             (b2 > t.lo2) && (b2 < t.hi2);
  *iou_out = iou;
  return ((cls + reg) + (-(iou * 0.25f))) + ((inb && inc) ? 0.0f : 100.0f);
}

// ---------------------------------------------------------------------------
// Fused select: one block per (b, g-pair).  Waves split the preds; per-lane
// streaming top-k in registers during the compute loop (no LDS staging),
// per-wave knockout -> 0.4 KB LDS fragments, block merge -> dyn + colsel +
// rowcnt/rowassign/worklist atomics.  Replaces stage1 + stage2.
__global__ __launch_bounds__(256) void select_kernel(
    const float* __restrict__ paux,
    const float* __restrict__ clst,
    const float* __restrict__ gtaux,
    const int* __restrict__ head_ptr,
    int* __restrict__ colsel,
    int* __restrict__ rowcnt,
    int* __restrict__ rowassign,
    int* __restrict__ wlist,
    int* __restrict__ wcount) {
#pragma clang fp contract(off)
  const int n = blockIdx.x;                   // 1024 = 8 * 128
  const int orig = (n & 7) * 128 + (n >> 3);  // XCD x -> b in {2x, 2x+1}
  const int b = orig >> 6;
  const int g0 = (orig & 63) * CPB;
  const int tid = threadIdx.x;
  const int lane = tid & 63, wid = tid >> 6;

  const GTp t0 = load_gt(gtaux, b, g0);
  const GTp t1 = load_gt(gtaux, b, g0 + 1);
  const size_t rowbase = (size_t)b * NP;

  uint32_t i0a = 0, i0b = 0, i0c = 0, i0d = 0, i0e = 0;
  uint32_t i1a = 0, i1b = 0, i1c = 0, i1d = 0, i1e = 0;
  u64 k0a = ~0ull, k0b = ~0ull, k0c = ~0ull, k0d = ~0ull;
  u64 k1a = ~0ull, k1b = ~0ull, k1c = ~0ull, k1d = ~0ull;

  for (int q = 0; q < QN; ++q) {
    const int p = q * 256 + tid;
    if (p < NP) {
      const size_t idx = rowbase + p;
      const float4* pa = (const float4*)(paux + idx * 16);
      float4 A = pa[0], B = pa[1], C = pa[2], D = pa[3];
      float cls0 = clst[(size_t)t0.label * NBPs + idx];
      float cls1 = clst[(size_t)t1.label * NBPs + idx];
      float iou0, iou1;
      float c0 = cost_base(A.x, A.y, A.z, A.w, B.x, B.y, B.z, B.w,
                           C.x, C.y, C.z, C.w, D.x, D.y, D.z,
                           cls0, t0, &iou0);
      float c1 = cost_base(A.x, A.y, A.z, A.w, B.x, B.y, B.z, B.w,
                           C.x, C.y, C.z, C.w, D.x, D.y, D.z,
                           cls1, t1, &iou1);
      ins5max(i0a, i0b, i0c, i0d, i0e, fkey(iou0));
      ins5max(i1a, i1b, i1c, i1d, i1e, fkey(iou1));
      ins4min(k0a, k0b, k0c, k0d, ((u64)fkey(c0 + D.w) << 32) | (unsigned)p);
      ins4min(k1a, k1b, k1c, k1d, ((u64)fkey(c1 + D.w) << 32) | (unsigned)p);
    }
  }

  __shared__ float iouF[4][CPB][5];
  __shared__ u64 ckF[4][CPB][4];
  wave_top5_iou(i0a, i0b, i0c, i0d, i0e, lane, &iouF[wid][0][0]);
  wave_top5_iou(i1a, i1b, i1c, i1d, i1e, lane, &iouF[wid][1][0]);
  wave_top4_cost(k0a, k0b, k0c, k0d, lane, &ckF[wid][0][0]);
  wave_top4_cost(k1a, k1b, k1c, k1d, lane, &ckF[wid][1][0]);
  __syncthreads();

  if (tid < CPB) {
    const int c = tid;
    const int g = g0 + c;
    const int col = b * NG + g;
    // merge 4 waves x 5 iou values -> global top-5 (value multiset)
    float m0 = -INFINITY, m1 = -INFINITY, m2 = -INFINITY, m3 = -INFINITY,
          m4 = -INFINITY;
    for (int w = 0; w < 4; ++w) {
      for (int j = 0; j < 5; ++j) {
        float v = iouF[w][c][j];
        if (v > m4) {
          m4 = v;
          if (m4 > m3) { float t = m4; m4 = m3; m3 = t; }
          if (m3 > m2) { float t = m3; m3 = m2; m2 = t; }
          if (m2 > m1) { float t = m2; m2 = m1; m1 = t; }
          if (m1 > m0) { float t = m1; m1 = m0; m0 = t; }
        }
      }
    }
    float sum5 = ((((m0 + m1) + m2) + m3) + m4);   // desc-order left-assoc
    float adj = sum5 - 0.5f * (float)(6 - head_ptr[0]);
    int dyn = (int)adj;              // trunc toward zero == astype(int32)
    if (dyn < 1) dyn = 1;
    if (dyn > SELMAX) dyn = SELMAX;
    // merge 4 waves x 4 cost keys -> global 4 smallest (stable: keys unique)
    u64 s0 = ~0ull, s1 = ~0ull, s2 = ~0ull, s3 = ~0ull;
    for (int w = 0; w < 4; ++w) {
      for (int j = 0; j < 4; ++j) {
        u64 k = ckF[w][c][j];
        if (k < s3) {
          s3 = k;
          if (s3 < s2) { u64 t = s3; s3 = s2; s2 = t; }
          if (s2 < s1) { u64 t = s2; s2 = s1; s1 = t; }
          if (s1 < s0) { u64 t = s1; s1 = s0; s0 = t; }
        }
      }
    }
    int pk0 = (int)(s0 & 0xffffffffu);
    int pk1 = (int)(s1 & 0xffffffffu);
    int pk2 = (int)(s2 & 0xffffffffu);
    int pk3 = (int)(s3 & 0xffffffffu);
    int sel0 = (dyn > 0) ? pk0 : -1;
    int sel1 = (dyn > 1) ? pk1 : -1;
    int sel2 = (dyn > 2) ? pk2 : -1;
    int sel3 = (dyn > 3) ? pk3 : -1;
    colsel[(size_t)col * SELMAX + 0] = sel0;
    colsel[(size_t)col * SELMAX + 1] = sel1;
    colsel[(size_t)col * SELMAX + 2] = sel2;
    colsel[(size_t)col * SELMAX + 3] = sel3;
    int sels[4] = {sel0, sel1, sel2, sel3};
    for (int k = 0; k < SELMAX; ++k) {
      int sel = sels[k];
      if (sel >= 0) {
        int old = atomicAdd(&rowcnt[rowbase + sel], 1);
        if (old == 1) {
          int slot = atomicAdd(wcount, 1);
          wlist[slot] = (int)(rowbase + sel);
        }
        atomicMin(&rowassign[rowbase + sel], g);
      }
    }
  }
}

// ---------------------------------------------------------------------------
// Epilogue: blocks [0,EPIW): one WAVE per prior row from the worklist —
// 128 g's spread 2-per-lane, parallel gathers, u64-key min reduce (key
// includes g -> first-g tiebreak).  Blocks [EPIW, EPIW+8): colcnt part (a).
__global__ __launch_bounds__(256) void epi_kernel(
    const float* __restrict__ paux,
    const float* __restrict__ clst,
    const float* __restrict__ gtaux,
    const int* __restrict__ colsel,
    const int* __restrict__ rowcnt,
    const int* __restrict__ wlist,
    const int* __restrict__ wcount,
    int* __restrict__ rowminArr,
    int* __restrict__ colcnt) {
#pragma clang fp contract(off)
  const int tid = threadIdx.x;
  if (blockIdx.x >= EPIW) {
    // colcnt part (a): selections whose row stayed single (rowcnt==1)
    const int col = (blockIdx.x - EPIW) * 256 + tid;
    if (col < NB * NG) {
      const int b = col / NG;
      int cnt = 0;
      const size_t cb = (size_t)col * SELMAX;
      for (int k = 0; k < SELMAX; ++k) {
        int s = colsel[cb + k];
        if (s >= 0 && rowcnt[(size_t)b * NP + s] == 1) cnt++;
      }
      if (cnt) atomicAdd(&colcnt[col], cnt);
    }
    return;
  }
  const int lane = tid & 63, wid = tid >> 6;
  const int wavesTotal = EPIW * 4;
  const int wave = blockIdx.x * 4 + wid;
  const int n = wcount[0];
  for (int e = wave; e < n; e += wavesTotal) {
    const int idx = wlist[e];
    const int b = idx / NP;
    const float4* pa = (const float4*)(paux + (size_t)idx * 16);
    float4 A = pa[0], Bq = pa[1], Cq = pa[2], Dq = pa[3];
    const float pen = Dq.w;
    u64 best = ~0ull;
    for (int h = 0; h < 2; ++h) {
      const int g = h * 64 + lane;
      GTp t = load_gt(gtaux, b, g);
      float cls = clst[(size_t)t.label * NBPs + idx];
      float iou;
      float cc = cost_base(A.x, A.y, A.z, A.w, Bq.x, Bq.y, Bq.z, Bq.w,
                           Cq.x, Cq.y, Cq.z, Cq.w, Dq.x, Dq.y, Dq.z,
                           cls, t, &iou);
      u64 key = ((u64)fkey(cc + pen) << 32) | (unsigned)g;
      if (key < best) best = key;
    }
    for (int o = 1; o < 64; o <<= 1) {
      u64 t = shfl_xor_u64(best, o);
      if (t < best) best = t;
    }
    if (lane == 0) {
      const int bg = (int)(best & 0xffffffffu);
      rowminArr[idx] = bg;
      atomicAdd(&colcnt[b * NG + bg], 1);
    }
  }
}

// Empty columns: recompute costs over never-matched rows, argmin (cost+pen,p).
__global__ __launch_bounds__(256) void fixup_kernel(
    const float* __restrict__ paux,
    const float* __restrict__ clst,
    const float* __restrict__ gtaux,
    const int* __restrict__ colcnt,
    const int* __restrict__ rowcnt,
    int* __restrict__ rowassign) {
#pragma clang fp contract(off)
  const int g = blockIdx.x, b = blockIdx.y, tid = threadIdx.x;
  if (colcnt[b * NG + g] != 0) return;  // uniform across block
  const int lane = tid & 63, wid = tid >> 6;
  const size_t rowbase = (size_t)b * NP;
  GTp t = load_gt(gtaux, b, g);
  u64 best = ~0ull;
  for (int p = tid; p < NP; p += 256) {
    const size_t idx = rowbase + p;
    if (rowcnt[idx] == 0) {
      const float4* pa = (const float4*)(paux + idx * 16);
      float4 A = pa[0], Bq = pa[1], Cq = pa[2], Dq = pa[3];
      float cls = clst[(size_t)t.label * NBPs + idx];
      float iou;
      float cc = cost_base(A.x, A.y, A.z, A.w, Bq.x, Bq.y, Bq.z, Bq.w,
                           Cq.x, Cq.y, Cq.z, Cq.w, Dq.x, Dq.y, Dq.z,
                           cls, t, &iou);
      u64 key = ((u64)fkey(cc + Dq.w) << 32) | (unsigned)p;
      if (key < best) best = key;
    }
  }
  __shared__ u64 sred[4];
  u64 rr = block_min_u64(best, sred, lane, wid);
  if (tid == 0) {
    int pos = (int)(rr & 0xffffffffu);
    atomicMin(&rowassign[rowbase + pos], g);  // min g == argmax first-1
  }
}

__global__ void output_kernel(const int* __restrict__ rowcnt,
                              const int* __restrict__ rowassign,
                              const int* __restrict__ rowminArr,
                              int* __restrict__ out) {
  const int i = blockIdx.x * 256 + threadIdx.x;
  if (i >= (int)NBPs) return;
  int rc = rowcnt[i];
  int fg, m;
  if (rc == 0) {
    int ra = rowassign[i];
    if (ra == 0x7fffffff) { fg = 0; m = -1; }
    else { fg = 1; m = ra; }          // fixup-assigned (min g)
  } else if (rc == 1) {
    fg = 1; m = rowassign[i];         // single selecting column
  } else {
    fg = 1; m = rowminArr[i];         // prior row -> one-hot at row argmin
  }
  out[i] = fg;
  out[NBPs + i] = m;
}

// ---------------------------------------------------------------------------
extern "C" void kernel_launch(void* const* d_in, const int* in_sizes, int n_in,
                              void* d_out, int out_size, void* d_ws, size_t ws_size,
                              hipStream_t stream) {
  const float* pred_logits = (const float*)d_in[0];
  const float* pred_boxes = (const float*)d_in[1];
  const float* gt_boxes = (const float*)d_in[2];
  const int* gt_labels = (const int*)d_in[3];
  const int* head = (const int*)d_in[4];
  (void)in_sizes; (void)n_in; (void)out_size; (void)ws_size;

  char* w = (char*)d_ws;
  size_t off = 0;
  auto alloc = [&](size_t bytes) -> void* {
    void* p = w + off;
    off += (bytes + 255) & ~(size_t)255;
    return p;
  };
  float* paux = (float*)alloc((size_t)NB * NP * 16 * 4);       // 6.1 MB
  float* clst = (float*)alloc((size_t)NC * NB * NP * 4);       // 3.8 MB
  float* gtaux = (float*)alloc((size_t)NB * NG * GSTR * 4);
  int* colsel = (int*)alloc((size_t)NB * NG * SELMAX * 4);
  int* rowcnt = (int*)alloc((size_t)NB * NP * 4);
  int* rowassign = (int*)alloc((size_t)NB * NP * 4);
  int* rowminArr = (int*)alloc((size_t)NB * NP * 4);
  int* colcnt = (int*)alloc((size_t)NB * NG * 4);
  int* wlist = (int*)alloc((size_t)NB * NP * 4);
  int* wcount = (int*)alloc(256);

  int* out = (int*)d_out;
  dim3 blk(256);
  prep_kernel<<<dim3((NP + 255) / 256, NB), blk, 0, stream>>>(
      gt_boxes, gt_labels, pred_logits, pred_boxes, gtaux, paux, clst,
      rowcnt, rowassign, colcnt, wcount);
  select_kernel<<<dim3(NB * NG / CPB), blk, 0, stream>>>(
      paux, clst, gtaux, head, colsel, rowcnt, rowassign, wlist, wcount);
  epi_kernel<<<dim3(EPIW + 8), blk, 0, stream>>>(
      paux, clst, gtaux, colsel, rowcnt, wlist, wcount, rowminArr, colcnt);
  fixup_kernel<<<dim3(NG, NB), blk, 0, stream>>>(
      paux, clst, gtaux, colcnt, rowcnt, rowassign);
  output_kernel<<<dim3(((int)NBPs + 255) / 256), blk, 0, stream>>>(
      rowcnt, rowassign, rowminArr, out);
}